// Round 1
// baseline (2011.982 us; speedup 1.0000x reference)
//
#include <hip/hip_runtime.h>
#include <hip/hip_bf16.h>
#include <math.h>

// Problem constants
#define Bn 4
#define Tn 1024
#define Cn 1024
#define Hn 16
#define Kn 64
#define DFn 2048

__device__ __forceinline__ float rdlane(float v, int l) {
  return __int_as_float(__builtin_amdgcn_readlane(__float_as_int(v), l));
}

// ---------------------------------------------------------------------------
// Kernel 1: xx = shift(x) - x ; xxx = x + xx*maa_x   (float4 elementwise)
// ---------------------------------------------------------------------------
__global__ __launch_bounds__(256) void k_prep(const float* __restrict__ x,
                                              const float* __restrict__ maa_x,
                                              float* __restrict__ xx,
                                              float* __restrict__ xxx) {
  int idx = blockIdx.x * 256 + threadIdx.x;   // float4 index over B*T*C/4
  int c4 = idx & 255;                          // C/4 = 256
  int bt = idx >> 8;
  int t = bt & (Tn - 1);
  const float4* x4 = (const float4*)x;
  float4 xv = x4[idx];
  float4 xp;
  if (t > 0) xp = x4[idx - 256];
  else { xp.x = 0.f; xp.y = 0.f; xp.z = 0.f; xp.w = 0.f; }
  float4 d;
  d.x = xp.x - xv.x; d.y = xp.y - xv.y; d.z = xp.z - xv.z; d.w = xp.w - xv.w;
  float4 m = ((const float4*)maa_x)[c4];
  float4 o;
  o.x = fmaf(d.x, m.x, xv.x);
  o.y = fmaf(d.y, m.y, xv.y);
  o.z = fmaf(d.z, m.z, xv.z);
  o.w = fmaf(d.w, m.w, xv.w);
  ((float4*)xx)[idx] = d;
  ((float4*)xxx)[idx] = o;
}

// ---------------------------------------------------------------------------
// Kernel 2: m1 = tanh(xxx @ w1)   (4096x1024)@(1024x96)
// block = 128 threads, 8 tokens per block (xxx rows staged in LDS)
// ---------------------------------------------------------------------------
__global__ __launch_bounds__(128) void k_mix1(const float* __restrict__ xxx,
                                              const float* __restrict__ w1,
                                              float* __restrict__ m1) {
  __shared__ float sx[8 * 1024];
  int tid = threadIdx.x;
  int tok0 = blockIdx.x * 8;
  const float4* src = (const float4*)(xxx + (size_t)tok0 * 1024);
  for (int i = tid; i < 8 * 256; i += 128) {
    ((float4*)sx)[i] = src[i];
  }
  __syncthreads();
  if (tid < 96) {
    float acc[8] = {0.f,0.f,0.f,0.f,0.f,0.f,0.f,0.f};
    for (int k = 0; k < 1024; ++k) {
      float wv = w1[k * 96 + tid];
      #pragma unroll
      for (int tt = 0; tt < 8; ++tt)
        acc[tt] = fmaf(sx[tt * 1024 + k], wv, acc[tt]);
    }
    #pragma unroll
    for (int tt = 0; tt < 8; ++tt)
      m1[(size_t)(tok0 + tt) * 96 + tid] = tanhf(acc[tt]);
  }
}

// ---------------------------------------------------------------------------
// Kernel 3: mk/mv/mr = m1 @ w2[l] ; xk/xv/xr = x + xx*(maa_* + m*)
// block = 256 threads, 4 tokens per block
// ---------------------------------------------------------------------------
__global__ __launch_bounds__(256) void k_mix2(const float* __restrict__ x,
                                              const float* __restrict__ xx,
                                              const float* __restrict__ m1,
                                              const float* __restrict__ w2,
                                              const float* __restrict__ maa_k,
                                              const float* __restrict__ maa_v,
                                              const float* __restrict__ maa_r,
                                              float* __restrict__ xk,
                                              float* __restrict__ xv,
                                              float* __restrict__ xr) {
  __shared__ float sm[4 * 96];
  int tid = threadIdx.x;
  int tok0 = blockIdx.x * 4;
  for (int i = tid; i < 4 * 96; i += 256)
    sm[i] = m1[(size_t)tok0 * 96 + i];
  __syncthreads();
  for (int cc = 0; cc < 4; ++cc) {
    int c = tid + cc * 256;
    float a0[4] = {0.f,0.f,0.f,0.f};
    float a1[4] = {0.f,0.f,0.f,0.f};
    float a2[4] = {0.f,0.f,0.f,0.f};
    for (int d = 0; d < 32; ++d) {
      float w0 = w2[(size_t)(0 * 32 + d) * 1024 + c];
      float w1v = w2[(size_t)(1 * 32 + d) * 1024 + c];
      float w2v = w2[(size_t)(2 * 32 + d) * 1024 + c];
      #pragma unroll
      for (int tt = 0; tt < 4; ++tt) {
        a0[tt] = fmaf(sm[tt * 96 + d], w0, a0[tt]);
        a1[tt] = fmaf(sm[tt * 96 + 32 + d], w1v, a1[tt]);
        a2[tt] = fmaf(sm[tt * 96 + 64 + d], w2v, a2[tt]);
      }
    }
    float mak = maa_k[c], mav = maa_v[c], mar = maa_r[c];
    #pragma unroll
    for (int tt = 0; tt < 4; ++tt) {
      size_t off = (size_t)(tok0 + tt) * 1024 + c;
      float xval = x[off], xxv = xx[off];
      xk[off] = fmaf(xxv, mak + a0[tt], xval);
      xv[off] = fmaf(xxv, mav + a1[tt], xval);
      xr[off] = fmaf(xxv, mar + a2[tt], xval);
    }
  }
}

// ---------------------------------------------------------------------------
// Generic tiled f32 GEMM: C = A(MxK) @ B(KxN), 64x64 tile, BK=16, 4x4/thread
// EPI: 0 = plain, 1 = exp(-exp(val))
// ---------------------------------------------------------------------------
template <int EPI>
__global__ __launch_bounds__(256) void k_gemm(const float* __restrict__ A,
                                              const float* __restrict__ Bmat,
                                              float* __restrict__ C,
                                              int M, int N, int K) {
  __shared__ float As[16][68];
  __shared__ float Bs[16][68];
  int tid = threadIdx.x;
  int row0 = blockIdx.y * 64, col0 = blockIdx.x * 64;
  int tx = tid & 15, ty = tid >> 4;
  int am = tid >> 2, ak = (tid & 3) << 2;
  int bk = tid >> 4, bn = (tid & 15) << 2;
  float acc[4][4] = {};
  for (int k0 = 0; k0 < K; k0 += 16) {
    float4 av = *(const float4*)&A[(size_t)(row0 + am) * K + k0 + ak];
    float4 bv = *(const float4*)&Bmat[(size_t)(k0 + bk) * N + col0 + bn];
    __syncthreads();
    As[ak + 0][am] = av.x; As[ak + 1][am] = av.y;
    As[ak + 2][am] = av.z; As[ak + 3][am] = av.w;
    *(float4*)&Bs[bk][bn] = bv;
    __syncthreads();
    #pragma unroll
    for (int kk = 0; kk < 16; ++kk) {
      float4 a4 = *(const float4*)&As[kk][ty << 2];
      float4 b4 = *(const float4*)&Bs[kk][tx << 2];
      float aa[4] = {a4.x, a4.y, a4.z, a4.w};
      float bb[4] = {b4.x, b4.y, b4.z, b4.w};
      #pragma unroll
      for (int i = 0; i < 4; ++i)
        #pragma unroll
        for (int j = 0; j < 4; ++j)
          acc[i][j] = fmaf(aa[i], bb[j], acc[i][j]);
    }
  }
  #pragma unroll
  for (int i = 0; i < 4; ++i) {
    #pragma unroll
    for (int j = 0; j < 4; ++j) {
      float val = acc[i][j];
      if (EPI == 1) val = expf(-expf(val));
      C[(size_t)(row0 + (ty << 2) + i) * N + col0 + (tx << 2) + j] = val;
    }
  }
}

// ---------------------------------------------------------------------------
// Wvg GEMM with fused SiLU gating: A(4096x1024) @ Wvg(1024x6144)
// gated[t, c] = vffn[t,c] * silu(gate[t,c]) for c in [0,3072)
//   c < 1024  -> v buffer          (for WKV)
//   c >= 1024 -> cat[:, c]         (ffn half of final concat)
// ---------------------------------------------------------------------------
__global__ __launch_bounds__(256) void k_gemm_vg(const float* __restrict__ A,
                                                 const float* __restrict__ Bmat,
                                                 float* __restrict__ v,
                                                 float* __restrict__ cat) {
  __shared__ float As[16][68];
  __shared__ float B1[16][68];
  __shared__ float B2[16][68];
  const int K = 1024, N = 6144;
  int tid = threadIdx.x;
  int row0 = blockIdx.y * 64, col0 = blockIdx.x * 64;
  int tx = tid & 15, ty = tid >> 4;
  int am = tid >> 2, ak = (tid & 3) << 2;
  int bk = tid >> 4, bn = (tid & 15) << 2;
  float acc1[4][4] = {};
  float acc2[4][4] = {};
  for (int k0 = 0; k0 < K; k0 += 16) {
    float4 av = *(const float4*)&A[(size_t)(row0 + am) * K + k0 + ak];
    float4 b1 = *(const float4*)&Bmat[(size_t)(k0 + bk) * N + col0 + bn];
    float4 b2 = *(const float4*)&Bmat[(size_t)(k0 + bk) * N + col0 + 3072 + bn];
    __syncthreads();
    As[ak + 0][am] = av.x; As[ak + 1][am] = av.y;
    As[ak + 2][am] = av.z; As[ak + 3][am] = av.w;
    *(float4*)&B1[bk][bn] = b1;
    *(float4*)&B2[bk][bn] = b2;
    __syncthreads();
    #pragma unroll
    for (int kk = 0; kk < 16; ++kk) {
      float4 a4 = *(const float4*)&As[kk][ty << 2];
      float4 b4 = *(const float4*)&B1[kk][tx << 2];
      float4 c4 = *(const float4*)&B2[kk][tx << 2];
      float aa[4] = {a4.x, a4.y, a4.z, a4.w};
      float bb[4] = {b4.x, b4.y, b4.z, b4.w};
      float gg[4] = {c4.x, c4.y, c4.z, c4.w};
      #pragma unroll
      for (int i = 0; i < 4; ++i)
        #pragma unroll
        for (int j = 0; j < 4; ++j) {
          acc1[i][j] = fmaf(aa[i], bb[j], acc1[i][j]);
          acc2[i][j] = fmaf(aa[i], gg[j], acc2[i][j]);
        }
    }
  }
  #pragma unroll
  for (int i = 0; i < 4; ++i) {
    #pragma unroll
    for (int j = 0; j < 4; ++j) {
      float g = acc2[i][j];
      float val = acc1[i][j] * (g / (1.f + expf(-g)));
      int colg = col0 + (tx << 2) + j;
      size_t row = (size_t)(row0 + (ty << 2) + i);
      if (colg < 1024) v[row * 1024 + colg] = val;
      else cat[row * 3072 + colg] = val;
    }
  }
}

// ---------------------------------------------------------------------------
// WKV6 recurrence. grid = B*H blocks, 256 threads = 4 waves.
// wave w owns state rows j in [16w, 16w+16); lane = v column (64).
// r/k/e broadcast via v_readlane; y reduced across waves via LDS.
// ---------------------------------------------------------------------------
__global__ __launch_bounds__(256) void k_wkv(const float* __restrict__ r,
                                             const float* __restrict__ e,
                                             const float* __restrict__ v,
                                             const float* __restrict__ u,
                                             float* __restrict__ o) {
  int bh = blockIdx.x;
  int b = bh >> 4, h = bh & 15;
  int tid = threadIdx.x, wave = tid >> 6, lane = tid & 63;
  size_t base = (size_t)b * Tn * Cn + (size_t)h * 64;
  int jbase = wave * 16 + (lane & 15);
  float uv = u[h * 64 + jbase];
  float st[16];
  #pragma unroll
  for (int i = 0; i < 16; ++i) st[i] = 0.f;
  __shared__ float yp[4][64];
  for (int t = 0; t < Tn; ++t) {
    size_t off = base + (size_t)t * Cn;
    float rv = r[off + jbase];
    float ev = e[off + jbase];
    float vv = v[off + lane];
    float y = 0.f;
    #pragma unroll
    for (int jj = 0; jj < 16; ++jj) {
      float rj = rdlane(rv, jj);
      float ej = rdlane(ev, jj);
      float uj = rdlane(uv, jj);
      float kv = (1.f - ej) * vv;       // k = 1 - e
      y = fmaf(rj, fmaf(uj, kv, st[jj]), y);
      st[jj] = fmaf(st[jj], ej, kv);
    }
    yp[wave][lane] = y;
    __syncthreads();
    if (wave == 0)
      o[off + lane] = yp[0][lane] + yp[1][lane] + yp[2][lane] + yp[3][lane];
    __syncthreads();
  }
}

// ---------------------------------------------------------------------------
// LayerNorm over C=1024, writes into cat[:, 0:1024]
// ---------------------------------------------------------------------------
__global__ __launch_bounds__(256) void k_ln(const float* __restrict__ o,
                                            const float* __restrict__ g,
                                            const float* __restrict__ bta,
                                            float* __restrict__ cat) {
  int bt = blockIdx.x, tid = threadIdx.x;
  const float4* row = (const float4*)(o + (size_t)bt * 1024);
  float4 v = row[tid];
  float s = v.x + v.y + v.z + v.w;
  float s2 = fmaf(v.x, v.x, fmaf(v.y, v.y, fmaf(v.z, v.z, v.w * v.w)));
  #pragma unroll
  for (int m = 1; m < 64; m <<= 1) {
    s += __shfl_xor(s, m, 64);
    s2 += __shfl_xor(s2, m, 64);
  }
  __shared__ float rs[4], rq[4];
  if ((tid & 63) == 0) { rs[tid >> 6] = s; rq[tid >> 6] = s2; }
  __syncthreads();
  s = rs[0] + rs[1] + rs[2] + rs[3];
  s2 = rq[0] + rq[1] + rq[2] + rq[3];
  float mu = s * (1.f / 1024.f);
  float var = s2 * (1.f / 1024.f) - mu * mu;
  float rstd = rsqrtf(var + 1e-5f);
  float4 gv = ((const float4*)g)[tid];
  float4 bv = ((const float4*)bta)[tid];
  float4 outv;
  outv.x = fmaf((v.x - mu) * rstd, gv.x, bv.x);
  outv.y = fmaf((v.y - mu) * rstd, gv.y, bv.y);
  outv.z = fmaf((v.z - mu) * rstd, gv.z, bv.z);
  outv.w = fmaf((v.w - mu) * rstd, gv.w, bv.w);
  ((float4*)(cat + (size_t)bt * 3072))[tid] = outv;
}

// ---------------------------------------------------------------------------
extern "C" void kernel_launch(void* const* d_in, const int* in_sizes, int n_in,
                              void* d_out, int out_size, void* d_ws, size_t ws_size,
                              hipStream_t stream) {
  const float* x     = (const float*)d_in[0];
  const float* maa_x = (const float*)d_in[1];
  const float* maa_k = (const float*)d_in[2];
  const float* maa_v = (const float*)d_in[3];
  const float* maa_r = (const float*)d_in[4];
  const float* w1    = (const float*)d_in[5];
  const float* w2    = (const float*)d_in[6];
  const float* u     = (const float*)d_in[7];
  const float* Wr    = (const float*)d_in[8];
  const float* Wk    = (const float*)d_in[9];
  const float* Wvg   = (const float*)d_in[10];
  const float* Wo    = (const float*)d_in[11];
  const float* ln_g  = (const float*)d_in[12];
  const float* ln_b  = (const float*)d_in[13];
  float* out = (float*)d_out;
  float* ws = (float*)d_ws;

  // Workspace layout (floats). Total = 34,078,720 floats = 130 MiB.
  const size_t M4 = 4194304;  // B*T*C
  float* xx  = ws;                       // 4M   (reused as o after k_mix2)
  float* xxx = ws + M4;                  // 4M   (reused as r after k_mix1)
  float* m1  = ws + 2 * M4;              // 0.5M
  float* xk  = ws + 2 * M4 + 524288;     // 4M
  float* xvb = ws + 3 * M4 + 524288;     // 4M   (reused as e after k_gemm_vg)
  float* xr  = ws + 4 * M4 + 524288;     // 4M   (reused as v after Wr gemm)
  float* cat = ws + 5 * M4 + 524288;     // 12M  (4096 x 3072 concat [ln(o) | ffn])
  float* rr = xxx;
  float* ee = xvb;
  float* vv = xr;
  float* oo = xx;

  k_prep<<<4096, 256, 0, stream>>>(x, maa_x, xx, xxx);
  k_mix1<<<512, 128, 0, stream>>>(xxx, w1, m1);
  k_mix2<<<1024, 256, 0, stream>>>(x, xx, m1, w2, maa_k, maa_v, maa_r, xk, xvb, xr);
  // r = xr @ Wr   (writes into xxx slot; xxx dead)
  k_gemm<0><<<dim3(16, 64), 256, 0, stream>>>(xr, Wr, rr, 4096, 1024, 1024);
  // gated vg = xv @ Wvg -> v (xr slot; xr dead after Wr gemm) + cat ffn half
  k_gemm_vg<<<dim3(48, 64), 256, 0, stream>>>(xvb, Wvg, vv, cat);
  // e = exp(-exp(xk @ Wk))  (writes into xv slot; xv dead)
  k_gemm<1><<<dim3(16, 64), 256, 0, stream>>>(xk, Wk, ee, 4096, 1024, 1024);
  // WKV6 recurrence -> o (xx slot; xx dead)
  k_wkv<<<64, 256, 0, stream>>>(rr, ee, vv, u, oo);
  // LayerNorm -> cat[:, 0:1024]
  k_ln<<<4096, 256, 0, stream>>>(oo, ln_g, ln_b, cat);
  // out = cat @ Wo
  k_gemm<0><<<dim3(16, 64), 256, 0, stream>>>(cat, Wo, out, 4096, 1024, 3072);
}

// Round 2
// 1537.228 us; speedup vs baseline: 1.3088x; 1.3088x over previous
//
#include <hip/hip_runtime.h>
#include <hip/hip_bf16.h>
#include <math.h>

// Problem constants
#define Bn 4
#define Tn 1024
#define Cn 1024
#define Hn 16
#define Kn 64
#define DFn 2048
#define NCn 16      // WKV chunks
#define Ln 64       // chunk length (NCn*Ln == Tn)

__device__ __forceinline__ float rdlane(float v, int l) {
  return __int_as_float(__builtin_amdgcn_readlane(__float_as_int(v), l));
}

// ---------------------------------------------------------------------------
// Kernel 1: xx = shift(x) - x ; xxx = x + xx*maa_x   (float4 elementwise)
// ---------------------------------------------------------------------------
__global__ __launch_bounds__(256) void k_prep(const float* __restrict__ x,
                                              const float* __restrict__ maa_x,
                                              float* __restrict__ xx,
                                              float* __restrict__ xxx) {
  int idx = blockIdx.x * 256 + threadIdx.x;   // float4 index over B*T*C/4
  int c4 = idx & 255;                          // C/4 = 256
  int bt = idx >> 8;
  int t = bt & (Tn - 1);
  const float4* x4 = (const float4*)x;
  float4 xv = x4[idx];
  float4 xp;
  if (t > 0) xp = x4[idx - 256];
  else { xp.x = 0.f; xp.y = 0.f; xp.z = 0.f; xp.w = 0.f; }
  float4 d;
  d.x = xp.x - xv.x; d.y = xp.y - xv.y; d.z = xp.z - xv.z; d.w = xp.w - xv.w;
  float4 m = ((const float4*)maa_x)[c4];
  float4 o;
  o.x = fmaf(d.x, m.x, xv.x);
  o.y = fmaf(d.y, m.y, xv.y);
  o.z = fmaf(d.z, m.z, xv.z);
  o.w = fmaf(d.w, m.w, xv.w);
  ((float4*)xx)[idx] = d;
  ((float4*)xxx)[idx] = o;
}

// ---------------------------------------------------------------------------
// Kernel 2: m1 = tanh(xxx @ w1)   (4096x1024)@(1024x96)
// ---------------------------------------------------------------------------
__global__ __launch_bounds__(128) void k_mix1(const float* __restrict__ xxx,
                                              const float* __restrict__ w1,
                                              float* __restrict__ m1) {
  __shared__ float sx[8 * 1024];
  int tid = threadIdx.x;
  int tok0 = blockIdx.x * 8;
  const float4* src = (const float4*)(xxx + (size_t)tok0 * 1024);
  for (int i = tid; i < 8 * 256; i += 128) {
    ((float4*)sx)[i] = src[i];
  }
  __syncthreads();
  if (tid < 96) {
    float acc[8] = {0.f,0.f,0.f,0.f,0.f,0.f,0.f,0.f};
    for (int k = 0; k < 1024; ++k) {
      float wv = w1[k * 96 + tid];
      #pragma unroll
      for (int tt = 0; tt < 8; ++tt)
        acc[tt] = fmaf(sx[tt * 1024 + k], wv, acc[tt]);
    }
    #pragma unroll
    for (int tt = 0; tt < 8; ++tt)
      m1[(size_t)(tok0 + tt) * 96 + tid] = tanhf(acc[tt]);
  }
}

// ---------------------------------------------------------------------------
// Kernel 3: mk/mv/mr = m1 @ w2[l] ; xk/xv/xr = x + xx*(maa_* + m*)
// ---------------------------------------------------------------------------
__global__ __launch_bounds__(256) void k_mix2(const float* __restrict__ x,
                                              const float* __restrict__ xx,
                                              const float* __restrict__ m1,
                                              const float* __restrict__ w2,
                                              const float* __restrict__ maa_k,
                                              const float* __restrict__ maa_v,
                                              const float* __restrict__ maa_r,
                                              float* __restrict__ xk,
                                              float* __restrict__ xv,
                                              float* __restrict__ xr) {
  __shared__ float sm[4 * 96];
  int tid = threadIdx.x;
  int tok0 = blockIdx.x * 4;
  for (int i = tid; i < 4 * 96; i += 256)
    sm[i] = m1[(size_t)tok0 * 96 + i];
  __syncthreads();
  for (int cc = 0; cc < 4; ++cc) {
    int c = tid + cc * 256;
    float a0[4] = {0.f,0.f,0.f,0.f};
    float a1[4] = {0.f,0.f,0.f,0.f};
    float a2[4] = {0.f,0.f,0.f,0.f};
    for (int d = 0; d < 32; ++d) {
      float w0 = w2[(size_t)(0 * 32 + d) * 1024 + c];
      float w1v = w2[(size_t)(1 * 32 + d) * 1024 + c];
      float w2v = w2[(size_t)(2 * 32 + d) * 1024 + c];
      #pragma unroll
      for (int tt = 0; tt < 4; ++tt) {
        a0[tt] = fmaf(sm[tt * 96 + d], w0, a0[tt]);
        a1[tt] = fmaf(sm[tt * 96 + 32 + d], w1v, a1[tt]);
        a2[tt] = fmaf(sm[tt * 96 + 64 + d], w2v, a2[tt]);
      }
    }
    float mak = maa_k[c], mav = maa_v[c], mar = maa_r[c];
    #pragma unroll
    for (int tt = 0; tt < 4; ++tt) {
      size_t off = (size_t)(tok0 + tt) * 1024 + c;
      float xval = x[off], xxv = xx[off];
      xk[off] = fmaf(xxv, mak + a0[tt], xval);
      xv[off] = fmaf(xxv, mav + a1[tt], xval);
      xr[off] = fmaf(xxv, mar + a2[tt], xval);
    }
  }
}

// ---------------------------------------------------------------------------
// Generic tiled f32 GEMM: C = A(MxK) @ B(KxN), 64x64 tile, BK=16, 4x4/thread
// EPI: 0 = plain, 1 = exp(-exp(val))
// ---------------------------------------------------------------------------
template <int EPI>
__global__ __launch_bounds__(256) void k_gemm(const float* __restrict__ A,
                                              const float* __restrict__ Bmat,
                                              float* __restrict__ C,
                                              int M, int N, int K) {
  __shared__ float As[16][68];
  __shared__ float Bs[16][68];
  int tid = threadIdx.x;
  int row0 = blockIdx.y * 64, col0 = blockIdx.x * 64;
  int tx = tid & 15, ty = tid >> 4;
  int am = tid >> 2, ak = (tid & 3) << 2;
  int bk = tid >> 4, bn = (tid & 15) << 2;
  float acc[4][4] = {};
  for (int k0 = 0; k0 < K; k0 += 16) {
    float4 av = *(const float4*)&A[(size_t)(row0 + am) * K + k0 + ak];
    float4 bv = *(const float4*)&Bmat[(size_t)(k0 + bk) * N + col0 + bn];
    __syncthreads();
    As[ak + 0][am] = av.x; As[ak + 1][am] = av.y;
    As[ak + 2][am] = av.z; As[ak + 3][am] = av.w;
    *(float4*)&Bs[bk][bn] = bv;
    __syncthreads();
    #pragma unroll
    for (int kk = 0; kk < 16; ++kk) {
      float4 a4 = *(const float4*)&As[kk][ty << 2];
      float4 b4 = *(const float4*)&Bs[kk][tx << 2];
      float aa[4] = {a4.x, a4.y, a4.z, a4.w};
      float bb[4] = {b4.x, b4.y, b4.z, b4.w};
      #pragma unroll
      for (int i = 0; i < 4; ++i)
        #pragma unroll
        for (int j = 0; j < 4; ++j)
          acc[i][j] = fmaf(aa[i], bb[j], acc[i][j]);
    }
  }
  #pragma unroll
  for (int i = 0; i < 4; ++i) {
    #pragma unroll
    for (int j = 0; j < 4; ++j) {
      float val = acc[i][j];
      if (EPI == 1) val = expf(-expf(val));
      C[(size_t)(row0 + (ty << 2) + i) * N + col0 + (tx << 2) + j] = val;
    }
  }
}

// ---------------------------------------------------------------------------
// Wvg GEMM with fused SiLU gating: A(4096x1024) @ Wvg(1024x6144)
//   gated col c < 1024  -> v buffer (4096x1024)
//   gated col c >= 1024 -> ffn buffer (4096x2048)
// ---------------------------------------------------------------------------
__global__ __launch_bounds__(256) void k_gemm_vg(const float* __restrict__ A,
                                                 const float* __restrict__ Bmat,
                                                 float* __restrict__ v,
                                                 float* __restrict__ ffn) {
  __shared__ float As[16][68];
  __shared__ float B1[16][68];
  __shared__ float B2[16][68];
  const int K = 1024, N = 6144;
  int tid = threadIdx.x;
  int row0 = blockIdx.y * 64, col0 = blockIdx.x * 64;
  int tx = tid & 15, ty = tid >> 4;
  int am = tid >> 2, ak = (tid & 3) << 2;
  int bk = tid >> 4, bn = (tid & 15) << 2;
  float acc1[4][4] = {};
  float acc2[4][4] = {};
  for (int k0 = 0; k0 < K; k0 += 16) {
    float4 av = *(const float4*)&A[(size_t)(row0 + am) * K + k0 + ak];
    float4 b1 = *(const float4*)&Bmat[(size_t)(k0 + bk) * N + col0 + bn];
    float4 b2 = *(const float4*)&Bmat[(size_t)(k0 + bk) * N + col0 + 3072 + bn];
    __syncthreads();
    As[ak + 0][am] = av.x; As[ak + 1][am] = av.y;
    As[ak + 2][am] = av.z; As[ak + 3][am] = av.w;
    *(float4*)&B1[bk][bn] = b1;
    *(float4*)&B2[bk][bn] = b2;
    __syncthreads();
    #pragma unroll
    for (int kk = 0; kk < 16; ++kk) {
      float4 a4 = *(const float4*)&As[kk][ty << 2];
      float4 b4 = *(const float4*)&B1[kk][tx << 2];
      float4 c4 = *(const float4*)&B2[kk][tx << 2];
      float aa[4] = {a4.x, a4.y, a4.z, a4.w};
      float bb[4] = {b4.x, b4.y, b4.z, b4.w};
      float gg[4] = {c4.x, c4.y, c4.z, c4.w};
      #pragma unroll
      for (int i = 0; i < 4; ++i)
        #pragma unroll
        for (int j = 0; j < 4; ++j) {
          acc1[i][j] = fmaf(aa[i], bb[j], acc1[i][j]);
          acc2[i][j] = fmaf(aa[i], gg[j], acc2[i][j]);
        }
    }
  }
  #pragma unroll
  for (int i = 0; i < 4; ++i) {
    #pragma unroll
    for (int j = 0; j < 4; ++j) {
      float g = acc2[i][j];
      float val = acc1[i][j] * (g / (1.f + expf(-g)));
      int colg = col0 + (tx << 2) + j;
      size_t row = (size_t)(row0 + (ty << 2) + i);
      if (colg < 1024) v[row * 1024 + colg] = val;
      else ffn[row * 2048 + (colg - 1024)] = val;
    }
  }
}

// ---------------------------------------------------------------------------
// WKV6 phase 1: per-chunk local recurrence from S=0.
// grid = B*H*NC blocks; wave w owns k-rows [16w,16w+16); lane = v column.
// Writes: o (local outputs), Dcum (per-step cumulative decay),
//         Inc (chunk state increment), Dtot (chunk total decay).
// ---------------------------------------------------------------------------
__global__ __launch_bounds__(256) void k_wkv1(const float* __restrict__ r,
                                              const float* __restrict__ e,
                                              const float* __restrict__ v,
                                              const float* __restrict__ u,
                                              float* __restrict__ o,
                                              float* __restrict__ Dcum,
                                              float* __restrict__ Dtot,
                                              float* __restrict__ Inc) {
  int blk = blockIdx.x;
  int c = blk & (NCn - 1);
  int bh = blk >> 4;
  int b = bh >> 4, h = bh & 15;
  int tid = threadIdx.x, wave = tid >> 6, lane = tid & 63;
  size_t base = (size_t)b * Tn * Cn + (size_t)h * 64 + (size_t)c * Ln * Cn;
  int jbase = wave * 16 + (lane & 15);
  float uv = u[h * 64 + jbase];
  float st[16];
  #pragma unroll
  for (int i = 0; i < 16; ++i) st[i] = 0.f;
  float cum = 1.f;
  __shared__ float yp[4][64];
  for (int t = 0; t < Ln; ++t) {
    size_t off = base + (size_t)t * Cn;
    float rv = r[off + jbase];
    float ev = e[off + jbase];
    float vv = v[off + lane];
    if (lane < 16) Dcum[off + jbase] = cum;
    cum *= ev;
    float y = 0.f;
    #pragma unroll
    for (int jj = 0; jj < 16; ++jj) {
      float rj = rdlane(rv, jj);
      float ej = rdlane(ev, jj);
      float uj = rdlane(uv, jj);
      float kv = (1.f - ej) * vv;       // k = 1 - e
      y = fmaf(rj, fmaf(uj, kv, st[jj]), y);
      st[jj] = fmaf(st[jj], ej, kv);
    }
    yp[wave][lane] = y;
    __syncthreads();
    if (wave == 0)
      o[off + lane] = yp[0][lane] + yp[1][lane] + yp[2][lane] + yp[3][lane];
    __syncthreads();
  }
  size_t sbase = ((size_t)bh * NCn + c) * 4096;
  #pragma unroll
  for (int jj = 0; jj < 16; ++jj)
    Inc[sbase + (size_t)(wave * 16 + jj) * 64 + lane] = st[jj];
  if (lane < 16)
    Dtot[((size_t)bh * NCn + c) * 64 + jbase] = cum;
}

// ---------------------------------------------------------------------------
// WKV6 phase 2: sequential combine of chunk states, in place.
// Buffer entry c: Inc_c on input, S_start_c on output.
// S_start_0 = 0; S_start_{c+1} = Dtot_c * S_start_c + Inc_c.
// grid = B*H blocks; each thread owns 16 state elements (4 float4).
// ---------------------------------------------------------------------------
__global__ __launch_bounds__(256) void k_wkv2(float* __restrict__ S,
                                              const float* __restrict__ Dtot) {
  int bh = blockIdx.x;
  int tid = threadIdx.x;
  float4 s[4];
  #pragma unroll
  for (int j = 0; j < 4; ++j) { s[j].x = 0.f; s[j].y = 0.f; s[j].z = 0.f; s[j].w = 0.f; }
  size_t sb = (size_t)bh * NCn * 4096;
  for (int c = 0; c < NCn; ++c) {
    float4* entry = (float4*)(S + sb + (size_t)c * 4096);
    const float* dt = Dtot + ((size_t)bh * NCn + c) * 64;
    #pragma unroll
    for (int j = 0; j < 4; ++j) {
      int idx4 = tid + j * 256;
      int k = idx4 >> 4;           // float offset /64
      float d = dt[k];
      float4 inc = entry[idx4];    // read Inc_c BEFORE overwrite
      float4 cur = s[j];
      entry[idx4] = cur;           // store S_start_c
      s[j].x = fmaf(cur.x, d, inc.x);
      s[j].y = fmaf(cur.y, d, inc.y);
      s[j].z = fmaf(cur.z, d, inc.z);
      s[j].w = fmaf(cur.w, d, inc.w);
    }
  }
}

// ---------------------------------------------------------------------------
// WKV6 phase 3: o_t += (r_t * Dcum_t) . S_start_{chunk(t)}
// grid = B*H*NC blocks (c==0 exits: S_start_0 = 0). lane = v; S column in regs.
// ---------------------------------------------------------------------------
__global__ __launch_bounds__(256) void k_wkv3(const float* __restrict__ r,
                                              const float* __restrict__ Dcum,
                                              const float* __restrict__ S,
                                              float* __restrict__ o) {
  int blk = blockIdx.x;
  int c = blk & (NCn - 1);
  if (c == 0) return;
  int bh = blk >> 4;
  int b = bh >> 4, h = bh & 15;
  int tid = threadIdx.x, wave = tid >> 6, lane = tid & 63;
  const float* Sg = S + ((size_t)bh * NCn + c) * 4096;
  float sreg[64];
  #pragma unroll
  for (int k = 0; k < 64; ++k) sreg[k] = Sg[k * 64 + lane];   // column v=lane
  size_t base = (size_t)b * Tn * Cn + (size_t)h * 64 + (size_t)c * Ln * Cn;
  for (int ti = 0; ti < 16; ++ti) {
    int t = wave * 16 + ti;
    size_t off = base + (size_t)t * Cn;
    float rd = r[off + lane] * Dcum[off + lane];
    float y = 0.f;
    #pragma unroll
    for (int k = 0; k < 64; ++k)
      y = fmaf(rdlane(rd, k), sreg[k], y);
    o[off + lane] += y;
  }
}

// ---------------------------------------------------------------------------
// LayerNorm over C=1024 -> ln_out (4096x1024)
// ---------------------------------------------------------------------------
__global__ __launch_bounds__(256) void k_ln(const float* __restrict__ o,
                                            const float* __restrict__ g,
                                            const float* __restrict__ bta,
                                            float* __restrict__ ln_out) {
  int bt = blockIdx.x, tid = threadIdx.x;
  const float4* row = (const float4*)(o + (size_t)bt * 1024);
  float4 v = row[tid];
  float s = v.x + v.y + v.z + v.w;
  float s2 = fmaf(v.x, v.x, fmaf(v.y, v.y, fmaf(v.z, v.z, v.w * v.w)));
  #pragma unroll
  for (int m = 1; m < 64; m <<= 1) {
    s += __shfl_xor(s, m, 64);
    s2 += __shfl_xor(s2, m, 64);
  }
  __shared__ float rs[4], rq[4];
  if ((tid & 63) == 0) { rs[tid >> 6] = s; rq[tid >> 6] = s2; }
  __syncthreads();
  s = rs[0] + rs[1] + rs[2] + rs[3];
  s2 = rq[0] + rq[1] + rq[2] + rq[3];
  float mu = s * (1.f / 1024.f);
  float var = s2 * (1.f / 1024.f) - mu * mu;
  float rstd = rsqrtf(var + 1e-5f);
  float4 gv = ((const float4*)g)[tid];
  float4 bv = ((const float4*)bta)[tid];
  float4 outv;
  outv.x = fmaf((v.x - mu) * rstd, gv.x, bv.x);
  outv.y = fmaf((v.y - mu) * rstd, gv.y, bv.y);
  outv.z = fmaf((v.z - mu) * rstd, gv.z, bv.z);
  outv.w = fmaf((v.w - mu) * rstd, gv.w, bv.w);
  ((float4*)(ln_out + (size_t)bt * 1024))[tid] = outv;
}

// ---------------------------------------------------------------------------
// Final GEMM: out(4096x1024) = ln_out(4096x1024) @ Wo[0:1024,:]
//                            + ffn(4096x2048)   @ Wo[1024:3072,:]
// ---------------------------------------------------------------------------
__global__ __launch_bounds__(256) void k_gemm_wo(const float* __restrict__ A1,
                                                 const float* __restrict__ A2,
                                                 const float* __restrict__ Bmat,
                                                 float* __restrict__ C) {
  __shared__ float As[16][68];
  __shared__ float Bs[16][68];
  const int N = 1024, K = 3072;
  int tid = threadIdx.x;
  int row0 = blockIdx.y * 64, col0 = blockIdx.x * 64;
  int tx = tid & 15, ty = tid >> 4;
  int am = tid >> 2, ak = (tid & 3) << 2;
  int bk = tid >> 4, bn = (tid & 15) << 2;
  float acc[4][4] = {};
  for (int k0 = 0; k0 < K; k0 += 16) {
    const float* Ap; int lda, kk0;
    if (k0 < 1024) { Ap = A1; lda = 1024; kk0 = k0; }
    else           { Ap = A2; lda = 2048; kk0 = k0 - 1024; }
    float4 av = *(const float4*)&Ap[(size_t)(row0 + am) * lda + kk0 + ak];
    float4 bv = *(const float4*)&Bmat[(size_t)(k0 + bk) * N + col0 + bn];
    __syncthreads();
    As[ak + 0][am] = av.x; As[ak + 1][am] = av.y;
    As[ak + 2][am] = av.z; As[ak + 3][am] = av.w;
    *(float4*)&Bs[bk][bn] = bv;
    __syncthreads();
    #pragma unroll
    for (int kk = 0; kk < 16; ++kk) {
      float4 a4 = *(const float4*)&As[kk][ty << 2];
      float4 b4 = *(const float4*)&Bs[kk][tx << 2];
      float aa[4] = {a4.x, a4.y, a4.z, a4.w};
      float bb[4] = {b4.x, b4.y, b4.z, b4.w};
      #pragma unroll
      for (int i = 0; i < 4; ++i)
        #pragma unroll
        for (int j = 0; j < 4; ++j)
          acc[i][j] = fmaf(aa[i], bb[j], acc[i][j]);
    }
  }
  #pragma unroll
  for (int i = 0; i < 4; ++i)
    #pragma unroll
    for (int j = 0; j < 4; ++j)
      C[(size_t)(row0 + (ty << 2) + i) * N + col0 + (tx << 2) + j] = acc[i][j];
}

// ---------------------------------------------------------------------------
extern "C" void kernel_launch(void* const* d_in, const int* in_sizes, int n_in,
                              void* d_out, int out_size, void* d_ws, size_t ws_size,
                              hipStream_t stream) {
  const float* x     = (const float*)d_in[0];
  const float* maa_x = (const float*)d_in[1];
  const float* maa_k = (const float*)d_in[2];
  const float* maa_v = (const float*)d_in[3];
  const float* maa_r = (const float*)d_in[4];
  const float* w1    = (const float*)d_in[5];
  const float* w2    = (const float*)d_in[6];
  const float* u     = (const float*)d_in[7];
  const float* Wr    = (const float*)d_in[8];
  const float* Wk    = (const float*)d_in[9];
  const float* Wvg   = (const float*)d_in[10];
  const float* Wo    = (const float*)d_in[11];
  const float* ln_g  = (const float*)d_in[12];
  const float* ln_b  = (const float*)d_in[13];
  float* out = (float*)d_out;
  float* ws = (float*)d_ws;

  // Workspace layout (floats). Total = 32.5M floats = 124 MiB.
  const size_t M4 = 4194304;              // B*T*C
  float* xx    = ws;                      // A: 4M   -> oo (wkv output)
  float* xxx   = ws + M4;                 // B: 4M   -> rr
  float* m1    = ws + 2 * M4;             // C: 0.5M -> Dtot (64K)
  float* xk    = ws + 2 * M4 + 524288;    // D: 4M   -> Dcum
  float* xvb   = ws + 3 * M4 + 524288;    // E: 4M   -> ee
  float* xr    = ws + 4 * M4 + 524288;    // F: 4M   -> vv
  float* ffn   = ws + 5 * M4 + 524288;    // G: 8M   (4096 x 2048)
  float* Sbuf  = ws + 7 * M4 + 524288;    // H: 4M   Inc/S_start -> ln_out
  float* rr = xxx;
  float* ee = xvb;
  float* vv = xr;
  float* oo = xx;
  float* Dcum = xk;
  float* Dtot = m1;
  float* ln_out = Sbuf;

  k_prep<<<4096, 256, 0, stream>>>(x, maa_x, xx, xxx);
  k_mix1<<<512, 128, 0, stream>>>(xxx, w1, m1);
  k_mix2<<<1024, 256, 0, stream>>>(x, xx, m1, w2, maa_k, maa_v, maa_r, xk, xvb, xr);
  // r = xr @ Wr  (into xxx slot)
  k_gemm<0><<<dim3(16, 64), 256, 0, stream>>>(xr, Wr, rr, 4096, 1024, 1024);
  // gated vg = xv @ Wvg -> v (xr slot) + ffn
  k_gemm_vg<<<dim3(48, 64), 256, 0, stream>>>(xvb, Wvg, vv, ffn);
  // e = exp(-exp(xk @ Wk))  (into xv slot; xk becomes free AFTER this)
  k_gemm<1><<<dim3(16, 64), 256, 0, stream>>>(xk, Wk, ee, 4096, 1024, 1024);
  // WKV6 chunk-parallel scan
  k_wkv1<<<64 * NCn, 256, 0, stream>>>(rr, ee, vv, u, oo, Dcum, Dtot, Sbuf);
  k_wkv2<<<64, 256, 0, stream>>>(Sbuf, Dtot);
  k_wkv3<<<64 * NCn, 256, 0, stream>>>(rr, Dcum, Sbuf, oo);
  // LayerNorm -> ln_out (Sbuf slot; S dead after wkv3)
  k_ln<<<4096, 256, 0, stream>>>(oo, ln_g, ln_b, ln_out);
  // out = [ln_out | ffn] @ Wo
  k_gemm_wo<<<dim3(16, 64), 256, 0, stream>>>(ln_out, ffn, Wo, out);
}

// Round 3
// 487.183 us; speedup vs baseline: 4.1298x; 3.1553x over previous
//
#include <hip/hip_runtime.h>
#include <hip/hip_bf16.h>
#include <math.h>

// Problem constants
#define Bn 4
#define Tn 1024
#define Cn 1024
#define Hn 16
#define Kn 64
#define DFn 2048
#define NCn 16      // WKV chunks
#define Ln 64       // chunk length (NCn*Ln == Tn)

typedef __bf16 bf16x8 __attribute__((ext_vector_type(8)));
typedef float f32x4 __attribute__((ext_vector_type(4)));

#define GLD(dst, src) \
  __builtin_amdgcn_global_load_lds((__attribute__((address_space(1))) const void*)(src), \
                                   (__attribute__((address_space(3))) void*)(dst), 16, 0, 0)

__device__ __forceinline__ float rdlane(float v, int l) {
  return __int_as_float(__builtin_amdgcn_readlane(__float_as_int(v), l));
}

__device__ __forceinline__ unsigned short bfbits(float f) {
  union { __hip_bfloat16 h; unsigned short u; } cv;
  cv.h = __float2bfloat16(f);
  return cv.u;
}

// ---------------------------------------------------------------------------
// Kernel 1: xx = shift(x) - x ; xxx = x + xx*maa_x
// ---------------------------------------------------------------------------
__global__ __launch_bounds__(256) void k_prep(const float* __restrict__ x,
                                              const float* __restrict__ maa_x,
                                              float* __restrict__ xx,
                                              float* __restrict__ xxx) {
  int idx = blockIdx.x * 256 + threadIdx.x;
  int c4 = idx & 255;
  int bt = idx >> 8;
  int t = bt & (Tn - 1);
  const float4* x4 = (const float4*)x;
  float4 xv = x4[idx];
  float4 xp;
  if (t > 0) xp = x4[idx - 256];
  else { xp.x = 0.f; xp.y = 0.f; xp.z = 0.f; xp.w = 0.f; }
  float4 d;
  d.x = xp.x - xv.x; d.y = xp.y - xv.y; d.z = xp.z - xv.z; d.w = xp.w - xv.w;
  float4 m = ((const float4*)maa_x)[c4];
  float4 o;
  o.x = fmaf(d.x, m.x, xv.x);
  o.y = fmaf(d.y, m.y, xv.y);
  o.z = fmaf(d.z, m.z, xv.z);
  o.w = fmaf(d.w, m.w, xv.w);
  ((float4*)xx)[idx] = d;
  ((float4*)xxx)[idx] = o;
}

// ---------------------------------------------------------------------------
// Kernel 2: m1 = tanh(xxx @ w1)
// ---------------------------------------------------------------------------
__global__ __launch_bounds__(128) void k_mix1(const float* __restrict__ xxx,
                                              const float* __restrict__ w1,
                                              float* __restrict__ m1) {
  __shared__ float sx[8 * 1024];
  int tid = threadIdx.x;
  int tok0 = blockIdx.x * 8;
  const float4* src = (const float4*)(xxx + (size_t)tok0 * 1024);
  for (int i = tid; i < 8 * 256; i += 128) {
    ((float4*)sx)[i] = src[i];
  }
  __syncthreads();
  if (tid < 96) {
    float acc[8] = {0.f,0.f,0.f,0.f,0.f,0.f,0.f,0.f};
    for (int k = 0; k < 1024; ++k) {
      float wv = w1[k * 96 + tid];
      #pragma unroll
      for (int tt = 0; tt < 8; ++tt)
        acc[tt] = fmaf(sx[tt * 1024 + k], wv, acc[tt]);
    }
    #pragma unroll
    for (int tt = 0; tt < 8; ++tt)
      m1[(size_t)(tok0 + tt) * 96 + tid] = tanhf(acc[tt]);
  }
}

// ---------------------------------------------------------------------------
// Kernel 3: mk/mv/mr = m1 @ w2[l] ; xk/xv/xr = x + xx*(maa_* + m*)  -> bf16
// ---------------------------------------------------------------------------
__global__ __launch_bounds__(256) void k_mix2(const float* __restrict__ x,
                                              const float* __restrict__ xx,
                                              const float* __restrict__ m1,
                                              const float* __restrict__ w2,
                                              const float* __restrict__ maa_k,
                                              const float* __restrict__ maa_v,
                                              const float* __restrict__ maa_r,
                                              __hip_bfloat16* __restrict__ xk,
                                              __hip_bfloat16* __restrict__ xv,
                                              __hip_bfloat16* __restrict__ xr) {
  __shared__ float sm[4 * 96];
  int tid = threadIdx.x;
  int tok0 = blockIdx.x * 4;
  for (int i = tid; i < 4 * 96; i += 256)
    sm[i] = m1[(size_t)tok0 * 96 + i];
  __syncthreads();
  for (int cc = 0; cc < 4; ++cc) {
    int c = tid + cc * 256;
    float a0[4] = {0.f,0.f,0.f,0.f};
    float a1[4] = {0.f,0.f,0.f,0.f};
    float a2[4] = {0.f,0.f,0.f,0.f};
    for (int d = 0; d < 32; ++d) {
      float w0 = w2[(size_t)(0 * 32 + d) * 1024 + c];
      float w1v = w2[(size_t)(1 * 32 + d) * 1024 + c];
      float w2v = w2[(size_t)(2 * 32 + d) * 1024 + c];
      #pragma unroll
      for (int tt = 0; tt < 4; ++tt) {
        a0[tt] = fmaf(sm[tt * 96 + d], w0, a0[tt]);
        a1[tt] = fmaf(sm[tt * 96 + 32 + d], w1v, a1[tt]);
        a2[tt] = fmaf(sm[tt * 96 + 64 + d], w2v, a2[tt]);
      }
    }
    float mak = maa_k[c], mav = maa_v[c], mar = maa_r[c];
    #pragma unroll
    for (int tt = 0; tt < 4; ++tt) {
      size_t off = (size_t)(tok0 + tt) * 1024 + c;
      float xval = x[off], xxv = xx[off];
      xk[off] = __float2bfloat16(fmaf(xxv, mak + a0[tt], xval));
      xv[off] = __float2bfloat16(fmaf(xxv, mav + a1[tt], xval));
      xr[off] = __float2bfloat16(fmaf(xxv, mar + a2[tt], xval));
    }
  }
}

// ---------------------------------------------------------------------------
// Convert+transpose: W (K x N, f32) -> Wt (N x K, bf16). grid (N/32, K/32).
// ---------------------------------------------------------------------------
__global__ __launch_bounds__(256) void k_cvt_t(const float* __restrict__ W,
                                               __hip_bfloat16* __restrict__ Wt,
                                               int K, int N) {
  __shared__ float tile[32][33];
  int n0 = blockIdx.x * 32, k0 = blockIdx.y * 32;
  int tid = threadIdx.x;
  int c = tid & 31, r = tid >> 5;   // r = 0..7
  #pragma unroll
  for (int i = 0; i < 4; ++i)
    tile[r + i * 8][c] = W[(size_t)(k0 + r + i * 8) * N + n0 + c];
  __syncthreads();
  #pragma unroll
  for (int i = 0; i < 4; ++i)
    Wt[(size_t)(n0 + r + i * 8) * K + k0 + c] = __float2bfloat16(tile[c][r + i * 8]);
}

// ---------------------------------------------------------------------------
// bf16 MFMA GEMM: C(f32) = A(M x K, bf16 row-major) @ Bt(N x K, bf16)^T
// Tile BM=128, BN=FN*32, BK=32. 4 waves (2x2), each 64 x BN/2.
// EPI: 0 plain, 1 exp(-exp(x))
// ---------------------------------------------------------------------------
template <int FN, int EPI>
__global__ __launch_bounds__(256) void k_gemm16(const __hip_bfloat16* __restrict__ A,
                                                const __hip_bfloat16* __restrict__ Bt,
                                                float* __restrict__ C,
                                                const int K, const int N) {
  constexpr int BN = FN * 32;
  constexpr int NISS = 8 + BN / 16;
  constexpr int PW = NISS / 4;
  __shared__ __align__(16) __hip_bfloat16 Al[128 * 32];
  __shared__ __align__(16) __hip_bfloat16 Bl[BN * 32];
  const int tid = threadIdx.x;
  const int wid = tid >> 6, lane = tid & 63;
  const int wr = wid >> 1, wc = wid & 1;
  const int row0 = blockIdx.y * 128, col0 = blockIdx.x * BN;
  const char* gsrc[PW];
  char* ldst[PW];
  #pragma unroll
  for (int i = 0; i < PW; ++i) {
    const int s = wid + i * 4;
    if (s < 8) {
      const int r = s * 16 + (lane >> 2);
      gsrc[i] = (const char*)(A + (size_t)(row0 + r) * K) + (lane & 3) * 16;
      ldst[i] = (char*)&Al[0] + s * 1024;
    } else {
      const int r = (s - 8) * 16 + (lane >> 2);
      gsrc[i] = (const char*)(Bt + (size_t)(col0 + r) * K) + (lane & 3) * 16;
      ldst[i] = (char*)&Bl[0] + (s - 8) * 1024;
    }
  }
  f32x4 acc[4][FN];
  #pragma unroll
  for (int i = 0; i < 4; ++i)
    #pragma unroll
    for (int j = 0; j < FN; ++j)
      acc[i][j] = (f32x4){0.f, 0.f, 0.f, 0.f};
  const int g = lane >> 4, m = lane & 15;
  for (int k0 = 0; k0 < K; k0 += 32) {
    #pragma unroll
    for (int i = 0; i < PW; ++i) GLD(ldst[i], gsrc[i]);
    #pragma unroll
    for (int i = 0; i < PW; ++i) gsrc[i] += 64;
    __syncthreads();
    bf16x8 af[4], bfr[FN];
    #pragma unroll
    for (int i = 0; i < 4; ++i)
      af[i] = *(const bf16x8*)&Al[(wr * 64 + i * 16 + m) * 32 + g * 8];
    #pragma unroll
    for (int j = 0; j < FN; ++j)
      bfr[j] = *(const bf16x8*)&Bl[(wc * (BN / 2) + j * 16 + m) * 32 + g * 8];
    #pragma unroll
    for (int i = 0; i < 4; ++i)
      #pragma unroll
      for (int j = 0; j < FN; ++j)
        acc[i][j] = __builtin_amdgcn_mfma_f32_16x16x32_bf16(af[i], bfr[j], acc[i][j], 0, 0, 0);
    __syncthreads();
  }
  #pragma unroll
  for (int i = 0; i < 4; ++i) {
    const int grow = row0 + wr * 64 + i * 16 + g * 4;
    #pragma unroll
    for (int j = 0; j < FN; ++j) {
      const int gcol = col0 + wc * (BN / 2) + j * 16 + m;
      #pragma unroll
      for (int e = 0; e < 4; ++e) {
        float val = acc[i][j][e];
        if (EPI == 1) val = expf(-expf(val));
        C[(size_t)(grow + e) * N + gcol] = val;
      }
    }
  }
}

// ---------------------------------------------------------------------------
// Fused Wvg GEMM: gated[r, c] = (A@B)[r,c] * silu((A@B)[r,c+3072])
// A: 4096x1024 bf16, Bt: 6144x1024 bf16. Tile 128 rows x 64 gated cols.
// c < 1024 -> v (f32); else -> ffn (bf16, stride 2048)
// ---------------------------------------------------------------------------
__global__ __launch_bounds__(256) void k_gemm_vg16(const __hip_bfloat16* __restrict__ A,
                                                   const __hip_bfloat16* __restrict__ Bt,
                                                   float* __restrict__ v,
                                                   __hip_bfloat16* __restrict__ ffn) {
  const int K = 1024;
  __shared__ __align__(16) __hip_bfloat16 Al[128 * 32];
  __shared__ __align__(16) __hip_bfloat16 B1l[64 * 32];
  __shared__ __align__(16) __hip_bfloat16 B2l[64 * 32];
  const int tid = threadIdx.x;
  const int wid = tid >> 6, lane = tid & 63;
  const int wr = wid >> 1, wc = wid & 1;
  const int row0 = blockIdx.y * 128, col0 = blockIdx.x * 64;
  const char* gsrc[4];
  char* ldst[4];
  #pragma unroll
  for (int i = 0; i < 4; ++i) {
    const int s = wid + i * 4;
    if (s < 8) {
      const int r = s * 16 + (lane >> 2);
      gsrc[i] = (const char*)(A + (size_t)(row0 + r) * K) + (lane & 3) * 16;
      ldst[i] = (char*)&Al[0] + s * 1024;
    } else if (s < 12) {
      const int r = col0 + (s - 8) * 16 + (lane >> 2);
      gsrc[i] = (const char*)(Bt + (size_t)r * K) + (lane & 3) * 16;
      ldst[i] = (char*)&B1l[0] + (s - 8) * 1024;
    } else {
      const int r = 3072 + col0 + (s - 12) * 16 + (lane >> 2);
      gsrc[i] = (const char*)(Bt + (size_t)r * K) + (lane & 3) * 16;
      ldst[i] = (char*)&B2l[0] + (s - 12) * 1024;
    }
  }
  f32x4 a1[4][2], a2[4][2];
  #pragma unroll
  for (int i = 0; i < 4; ++i)
    #pragma unroll
    for (int j = 0; j < 2; ++j) {
      a1[i][j] = (f32x4){0.f, 0.f, 0.f, 0.f};
      a2[i][j] = (f32x4){0.f, 0.f, 0.f, 0.f};
    }
  const int g = lane >> 4, m = lane & 15;
  for (int k0 = 0; k0 < K; k0 += 32) {
    #pragma unroll
    for (int i = 0; i < 4; ++i) GLD(ldst[i], gsrc[i]);
    #pragma unroll
    for (int i = 0; i < 4; ++i) gsrc[i] += 64;
    __syncthreads();
    bf16x8 af[4], b1f[2], b2f[2];
    #pragma unroll
    for (int i = 0; i < 4; ++i)
      af[i] = *(const bf16x8*)&Al[(wr * 64 + i * 16 + m) * 32 + g * 8];
    #pragma unroll
    for (int j = 0; j < 2; ++j) {
      b1f[j] = *(const bf16x8*)&B1l[(wc * 32 + j * 16 + m) * 32 + g * 8];
      b2f[j] = *(const bf16x8*)&B2l[(wc * 32 + j * 16 + m) * 32 + g * 8];
    }
    #pragma unroll
    for (int i = 0; i < 4; ++i)
      #pragma unroll
      for (int j = 0; j < 2; ++j) {
        a1[i][j] = __builtin_amdgcn_mfma_f32_16x16x32_bf16(af[i], b1f[j], a1[i][j], 0, 0, 0);
        a2[i][j] = __builtin_amdgcn_mfma_f32_16x16x32_bf16(af[i], b2f[j], a2[i][j], 0, 0, 0);
      }
    __syncthreads();
  }
  const bool to_v = (col0 < 1024);
  #pragma unroll
  for (int i = 0; i < 4; ++i) {
    const int grow = row0 + wr * 64 + i * 16 + g * 4;
    #pragma unroll
    for (int j = 0; j < 2; ++j) {
      const int gcol = col0 + wc * 32 + j * 16 + m;
      #pragma unroll
      for (int e = 0; e < 4; ++e) {
        float gate = a2[i][j][e];
        float val = a1[i][j][e] * (gate / (1.f + expf(-gate)));
        if (to_v) v[(size_t)(grow + e) * 1024 + gcol] = val;
        else ffn[(size_t)(grow + e) * 2048 + (gcol - 1024)] = __float2bfloat16(val);
      }
    }
  }
}

// ---------------------------------------------------------------------------
// Final GEMM: out = [ln16 (4096x1024) | ffn16 (4096x2048)] @ Wo_t^T
// Wo_t: 1024 x 3072 bf16 (transposed). BN=64 tiles.
// ---------------------------------------------------------------------------
__global__ __launch_bounds__(256) void k_gemm_wo16(const __hip_bfloat16* __restrict__ A1,
                                                   const __hip_bfloat16* __restrict__ A2,
                                                   const __hip_bfloat16* __restrict__ Bt,
                                                   float* __restrict__ C) {
  const int Kt = 3072;
  __shared__ __align__(16) __hip_bfloat16 Al[128 * 32];
  __shared__ __align__(16) __hip_bfloat16 Bl[64 * 32];
  const int tid = threadIdx.x;
  const int wid = tid >> 6, lane = tid & 63;
  const int wr = wid >> 1, wc = wid & 1;
  const int row0 = blockIdx.y * 128, col0 = blockIdx.x * 64;
  const char* gsrc[3];
  char* ldst[3];
  #pragma unroll
  for (int i = 0; i < 3; ++i) {
    const int s = wid + i * 4;
    if (s < 8) {
      const int r = s * 16 + (lane >> 2);
      gsrc[i] = (const char*)(A1 + (size_t)(row0 + r) * 1024) + (lane & 3) * 16;
      ldst[i] = (char*)&Al[0] + s * 1024;
    } else {
      const int r = col0 + (s - 8) * 16 + (lane >> 2);
      gsrc[i] = (const char*)(Bt + (size_t)r * Kt) + (lane & 3) * 16;
      ldst[i] = (char*)&Bl[0] + (s - 8) * 1024;
    }
  }
  f32x4 acc[4][2];
  #pragma unroll
  for (int i = 0; i < 4; ++i)
    #pragma unroll
    for (int j = 0; j < 2; ++j)
      acc[i][j] = (f32x4){0.f, 0.f, 0.f, 0.f};
  const int g = lane >> 4, m = lane & 15;

  #define WO_STEP() do {                                                          \
    _Pragma("unroll")                                                             \
    for (int i = 0; i < 3; ++i) GLD(ldst[i], gsrc[i]);                            \
    _Pragma("unroll")                                                             \
    for (int i = 0; i < 3; ++i) gsrc[i] += 64;                                    \
    __syncthreads();                                                              \
    bf16x8 af[4], bfr[2];                                                         \
    _Pragma("unroll")                                                             \
    for (int i = 0; i < 4; ++i)                                                   \
      af[i] = *(const bf16x8*)&Al[(wr * 64 + i * 16 + m) * 32 + g * 8];           \
    _Pragma("unroll")                                                             \
    for (int j = 0; j < 2; ++j)                                                   \
      bfr[j] = *(const bf16x8*)&Bl[(wc * 32 + j * 16 + m) * 32 + g * 8];          \
    _Pragma("unroll")                                                             \
    for (int i = 0; i < 4; ++i)                                                   \
      _Pragma("unroll")                                                           \
      for (int j = 0; j < 2; ++j)                                                 \
        acc[i][j] = __builtin_amdgcn_mfma_f32_16x16x32_bf16(af[i], bfr[j],        \
                                                            acc[i][j], 0, 0, 0); \
    __syncthreads();                                                              \
  } while (0)

  for (int k0 = 0; k0 < 1024; k0 += 32) WO_STEP();
  // switch A source to ffn (stride 2048)
  #pragma unroll
  for (int i = 0; i < 3; ++i) {
    const int s = wid + i * 4;
    if (s < 8) {
      const int r = s * 16 + (lane >> 2);
      gsrc[i] = (const char*)(A2 + (size_t)(row0 + r) * 2048) + (lane & 3) * 16;
    }
  }
  for (int k0 = 0; k0 < 2048; k0 += 32) WO_STEP();
  #undef WO_STEP

  #pragma unroll
  for (int i = 0; i < 4; ++i) {
    const int grow = row0 + wr * 64 + i * 16 + g * 4;
    #pragma unroll
    for (int j = 0; j < 2; ++j) {
      const int gcol = col0 + wc * 32 + j * 16 + m;
      #pragma unroll
      for (int e = 0; e < 4; ++e)
        C[(size_t)(grow + e) * 1024 + gcol] = acc[i][j][e];
    }
  }
}

// ---------------------------------------------------------------------------
// WKV6 phase 1: per-chunk local recurrence from S=0.
// ---------------------------------------------------------------------------
__global__ __launch_bounds__(256) void k_wkv1(const float* __restrict__ r,
                                              const float* __restrict__ e,
                                              const float* __restrict__ v,
                                              const float* __restrict__ u,
                                              float* __restrict__ o,
                                              float* __restrict__ Dcum,
                                              float* __restrict__ Dtot,
                                              float* __restrict__ Inc) {
  int blk = blockIdx.x;
  int c = blk & (NCn - 1);
  int bh = blk >> 4;
  int b = bh >> 4, h = bh & 15;
  int tid = threadIdx.x, wave = tid >> 6, lane = tid & 63;
  size_t base = (size_t)b * Tn * Cn + (size_t)h * 64 + (size_t)c * Ln * Cn;
  int jbase = wave * 16 + (lane & 15);
  float uv = u[h * 64 + jbase];
  float st[16];
  #pragma unroll
  for (int i = 0; i < 16; ++i) st[i] = 0.f;
  float cum = 1.f;
  __shared__ float yp[4][64];
  for (int t = 0; t < Ln; ++t) {
    size_t off = base + (size_t)t * Cn;
    float rv = r[off + jbase];
    float ev = e[off + jbase];
    float vv = v[off + lane];
    if (lane < 16) Dcum[off + jbase] = cum;
    cum *= ev;
    float y = 0.f;
    #pragma unroll
    for (int jj = 0; jj < 16; ++jj) {
      float rj = rdlane(rv, jj);
      float ej = rdlane(ev, jj);
      float uj = rdlane(uv, jj);
      float kv = (1.f - ej) * vv;       // k = 1 - e
      y = fmaf(rj, fmaf(uj, kv, st[jj]), y);
      st[jj] = fmaf(st[jj], ej, kv);
    }
    yp[wave][lane] = y;
    __syncthreads();
    if (wave == 0)
      o[off + lane] = yp[0][lane] + yp[1][lane] + yp[2][lane] + yp[3][lane];
    __syncthreads();
  }
  size_t sbase = ((size_t)bh * NCn + c) * 4096;
  #pragma unroll
  for (int jj = 0; jj < 16; ++jj)
    Inc[sbase + (size_t)(wave * 16 + jj) * 64 + lane] = st[jj];
  if (lane < 16)
    Dtot[((size_t)bh * NCn + c) * 64 + jbase] = cum;
}

// ---------------------------------------------------------------------------
// WKV6 phase 2: sequential combine of chunk states, in place.
// ---------------------------------------------------------------------------
__global__ __launch_bounds__(256) void k_wkv2(float* __restrict__ S,
                                              const float* __restrict__ Dtot) {
  int bh = blockIdx.x;
  int tid = threadIdx.x;
  float4 s[4];
  #pragma unroll
  for (int j = 0; j < 4; ++j) { s[j].x = 0.f; s[j].y = 0.f; s[j].z = 0.f; s[j].w = 0.f; }
  size_t sb = (size_t)bh * NCn * 4096;
  for (int c = 0; c < NCn; ++c) {
    float4* entry = (float4*)(S + sb + (size_t)c * 4096);
    const float* dt = Dtot + ((size_t)bh * NCn + c) * 64;
    #pragma unroll
    for (int j = 0; j < 4; ++j) {
      int idx4 = tid + j * 256;
      int k = idx4 >> 4;
      float d = dt[k];
      float4 inc = entry[idx4];
      float4 cur = s[j];
      entry[idx4] = cur;
      s[j].x = fmaf(cur.x, d, inc.x);
      s[j].y = fmaf(cur.y, d, inc.y);
      s[j].z = fmaf(cur.z, d, inc.z);
      s[j].w = fmaf(cur.w, d, inc.w);
    }
  }
}

// ---------------------------------------------------------------------------
// WKV6 phase 3: o_t += (r_t * Dcum_t) . S_start_{chunk(t)}
// ---------------------------------------------------------------------------
__global__ __launch_bounds__(256) void k_wkv3(const float* __restrict__ r,
                                              const float* __restrict__ Dcum,
                                              const float* __restrict__ S,
                                              float* __restrict__ o) {
  int blk = blockIdx.x;
  int c = blk & (NCn - 1);
  if (c == 0) return;
  int bh = blk >> 4;
  int b = bh >> 4, h = bh & 15;
  int tid = threadIdx.x, wave = tid >> 6, lane = tid & 63;
  const float* Sg = S + ((size_t)bh * NCn + c) * 4096;
  float sreg[64];
  #pragma unroll
  for (int k = 0; k < 64; ++k) sreg[k] = Sg[k * 64 + lane];
  size_t base = (size_t)b * Tn * Cn + (size_t)h * 64 + (size_t)c * Ln * Cn;
  for (int ti = 0; ti < 16; ++ti) {
    int t = wave * 16 + ti;
    size_t off = base + (size_t)t * Cn;
    float rd = r[off + lane] * Dcum[off + lane];
    float y = 0.f;
    #pragma unroll
    for (int k = 0; k < 64; ++k)
      y = fmaf(rdlane(rd, k), sreg[k], y);
    o[off + lane] += y;
  }
}

// ---------------------------------------------------------------------------
// LayerNorm over C=1024 -> ln16 (bf16 4096x1024)
// ---------------------------------------------------------------------------
__global__ __launch_bounds__(256) void k_ln(const float* __restrict__ o,
                                            const float* __restrict__ g,
                                            const float* __restrict__ bta,
                                            __hip_bfloat16* __restrict__ ln16) {
  int bt = blockIdx.x, tid = threadIdx.x;
  const float4* row = (const float4*)(o + (size_t)bt * 1024);
  float4 v = row[tid];
  float s = v.x + v.y + v.z + v.w;
  float s2 = fmaf(v.x, v.x, fmaf(v.y, v.y, fmaf(v.z, v.z, v.w * v.w)));
  #pragma unroll
  for (int m = 1; m < 64; m <<= 1) {
    s += __shfl_xor(s, m, 64);
    s2 += __shfl_xor(s2, m, 64);
  }
  __shared__ float rs[4], rq[4];
  if ((tid & 63) == 0) { rs[tid >> 6] = s; rq[tid >> 6] = s2; }
  __syncthreads();
  s = rs[0] + rs[1] + rs[2] + rs[3];
  s2 = rq[0] + rq[1] + rq[2] + rq[3];
  float mu = s * (1.f / 1024.f);
  float var = s2 * (1.f / 1024.f) - mu * mu;
  float rstd = rsqrtf(var + 1e-5f);
  float4 gv = ((const float4*)g)[tid];
  float4 bv = ((const float4*)bta)[tid];
  ushort4 outv;
  outv.x = bfbits(fmaf((v.x - mu) * rstd, gv.x, bv.x));
  outv.y = bfbits(fmaf((v.y - mu) * rstd, gv.y, bv.y));
  outv.z = bfbits(fmaf((v.z - mu) * rstd, gv.z, bv.z));
  outv.w = bfbits(fmaf((v.w - mu) * rstd, gv.w, bv.w));
  ((ushort4*)((unsigned short*)ln16 + (size_t)bt * 1024))[tid] = outv;
}

// ---------------------------------------------------------------------------
extern "C" void kernel_launch(void* const* d_in, const int* in_sizes, int n_in,
                              void* d_out, int out_size, void* d_ws, size_t ws_size,
                              hipStream_t stream) {
  const float* x     = (const float*)d_in[0];
  const float* maa_x = (const float*)d_in[1];
  const float* maa_k = (const float*)d_in[2];
  const float* maa_v = (const float*)d_in[3];
  const float* maa_r = (const float*)d_in[4];
  const float* w1    = (const float*)d_in[5];
  const float* w2    = (const float*)d_in[6];
  const float* u     = (const float*)d_in[7];
  const float* Wr    = (const float*)d_in[8];
  const float* Wk    = (const float*)d_in[9];
  const float* Wvg   = (const float*)d_in[10];
  const float* Wo    = (const float*)d_in[11];
  const float* ln_g  = (const float*)d_in[12];
  const float* ln_b  = (const float*)d_in[13];
  float* out = (float*)d_out;
  float* ws = (float*)d_ws;

  // Workspace layout (floats), total 36M floats = 144 MB.
  const size_t M1 = 1048576;
  float* xx    = ws;                        //  0   .. 4M   f32  -> oo
  float* xxx   = ws + 4 * M1;               //  4M  .. 8M   f32  -> rr
  float* m1    = ws + 8 * M1;               //  8M  .. 8.5M f32  -> Dtot
  __hip_bfloat16* xk16 = (__hip_bfloat16*)(ws + 8 * M1 + 524288);   // 8.5M..10.5M
  __hip_bfloat16* xv16 = (__hip_bfloat16*)(ws + 10 * M1 + 524288);  // 10.5M..12.5M
  __hip_bfloat16* xr16 = (__hip_bfloat16*)(ws + 12 * M1 + 524288);  // 12.5M..14.5M
  float* ee    = ws + 14 * M1 + 524288;     // 14.5M..18.5M f32
  float* vv    = ws + 18 * M1 + 524288;     // 18.5M..22.5M f32
  float* Sbuf  = ws + 22 * M1 + 524288;     // 22.5M..26.5M f32 Inc/S_start -> ln16
  __hip_bfloat16* ffn16 = (__hip_bfloat16*)(ws + 26 * M1 + 524288); // 26.5M..30.5M
  __hip_bfloat16* Wr16t = (__hip_bfloat16*)(ws + 30 * M1 + 524288); // 0.5M floats
  __hip_bfloat16* Wk16t = (__hip_bfloat16*)(ws + 31 * M1);          // 0.5M floats
  __hip_bfloat16* Wvg16t = (__hip_bfloat16*)(ws + 31 * M1 + 524288);// 3M floats
  __hip_bfloat16* Wo16t = (__hip_bfloat16*)(ws + 34 * M1 + 524288); // 1.5M floats
  float* rr = xxx;
  float* oo = xx;
  float* Dcum = ws + 8 * M1 + 524288;       // overlaps xk16/xv16 (dead by wkv1)
  float* Dtot = m1;
  __hip_bfloat16* ln16 = (__hip_bfloat16*)Sbuf;  // after wkv3

  // weight converts (B^T bf16)
  k_cvt_t<<<dim3(32, 32), 256, 0, stream>>>(Wr, Wr16t, 1024, 1024);
  k_cvt_t<<<dim3(32, 32), 256, 0, stream>>>(Wk, Wk16t, 1024, 1024);
  k_cvt_t<<<dim3(192, 32), 256, 0, stream>>>(Wvg, Wvg16t, 1024, 6144);
  k_cvt_t<<<dim3(32, 96), 256, 0, stream>>>(Wo, Wo16t, 3072, 1024);

  k_prep<<<4096, 256, 0, stream>>>(x, maa_x, xx, xxx);
  k_mix1<<<512, 128, 0, stream>>>(xxx, w1, m1);
  k_mix2<<<1024, 256, 0, stream>>>(x, xx, m1, w2, maa_k, maa_v, maa_r, xk16, xv16, xr16);
  // r = xr @ Wr (f32 out into xxx slot)
  k_gemm16<2, 0><<<dim3(16, 32), 256, 0, stream>>>(xr16, Wr16t, rr, 1024, 1024);
  // gated vg = xv @ Wvg -> v (f32) + ffn (bf16)
  k_gemm_vg16<<<dim3(48, 32), 256, 0, stream>>>(xv16, Wvg16t, vv, ffn16);
  // e = exp(-exp(xk @ Wk)) (f32)
  k_gemm16<2, 1><<<dim3(16, 32), 256, 0, stream>>>(xk16, Wk16t, ee, 1024, 1024);
  // WKV6 chunk-parallel scan
  k_wkv1<<<64 * NCn, 256, 0, stream>>>(rr, ee, vv, u, oo, Dcum, Dtot, Sbuf);
  k_wkv2<<<64, 256, 0, stream>>>(Sbuf, Dtot);
  k_wkv3<<<64 * NCn, 256, 0, stream>>>(rr, Dcum, Sbuf, oo);
  // LayerNorm -> bf16 (Sbuf slot, S dead after wkv3)
  k_ln<<<4096, 256, 0, stream>>>(oo, ln_g, ln_b, ln16);
  // out = [ln16 | ffn16] @ Wo
  k_gemm_wo16<<<dim3(16, 32), 256, 0, stream>>>(ln16, ffn16, Wo16t, out);
}

// Round 4
// 432.492 us; speedup vs baseline: 4.6521x; 1.1265x over previous
//
#include <hip/hip_runtime.h>
#include <hip/hip_bf16.h>
#include <math.h>

// Problem constants
#define Bn 4
#define Tn 1024
#define Cn 1024
#define Hn 16
#define Kn 64
#define DFn 2048
#define NCn 16      // WKV chunks
#define Ln 64       // chunk length (NCn*Ln == Tn)

typedef __bf16 bf16x8 __attribute__((ext_vector_type(8)));
typedef float f32x4 __attribute__((ext_vector_type(4)));

#define GLD(dst, src) \
  __builtin_amdgcn_global_load_lds((__attribute__((address_space(1))) const void*)(src), \
                                   (__attribute__((address_space(3))) void*)(dst), 16, 0, 0)

__device__ __forceinline__ float rdlane(float v, int l) {
  return __int_as_float(__builtin_amdgcn_readlane(__float_as_int(v), l));
}

__device__ __forceinline__ unsigned short bfbits(float f) {
  union { __hip_bfloat16 h; unsigned short u; } cv;
  cv.h = __float2bfloat16(f);
  return cv.u;
}

// ---------------------------------------------------------------------------
// Kernel 1: xx = shift(x) - x (f32) ; xxx = x + xx*maa_x (bf16, feeds mix1)
// ---------------------------------------------------------------------------
__global__ __launch_bounds__(256) void k_prep(const float* __restrict__ x,
                                              const float* __restrict__ maa_x,
                                              float* __restrict__ xx,
                                              __hip_bfloat16* __restrict__ xxx16) {
  int idx = blockIdx.x * 256 + threadIdx.x;
  int c4 = idx & 255;
  int bt = idx >> 8;
  int t = bt & (Tn - 1);
  const float4* x4 = (const float4*)x;
  float4 xv = x4[idx];
  float4 xp;
  if (t > 0) xp = x4[idx - 256];
  else { xp.x = 0.f; xp.y = 0.f; xp.z = 0.f; xp.w = 0.f; }
  float4 d;
  d.x = xp.x - xv.x; d.y = xp.y - xv.y; d.z = xp.z - xv.z; d.w = xp.w - xv.w;
  float4 m = ((const float4*)maa_x)[c4];
  ushort4 o;
  o.x = bfbits(fmaf(d.x, m.x, xv.x));
  o.y = bfbits(fmaf(d.y, m.y, xv.y));
  o.z = bfbits(fmaf(d.z, m.z, xv.z));
  o.w = bfbits(fmaf(d.w, m.w, xv.w));
  ((float4*)xx)[idx] = d;
  ((ushort4*)xxx16)[idx] = o;
}

// ---------------------------------------------------------------------------
// Kernel 2 (MFMA): m1 = tanh(xxx16 @ w1t^T)   (4096x1024)@(1024x96)
// BM=128, BN=96 (3 frags/wave, 2x2 waves), BK=32; 14 staging subtiles/K-step.
// ---------------------------------------------------------------------------
__global__ __launch_bounds__(256) void k_mix1_16(const __hip_bfloat16* __restrict__ A,
                                                 const __hip_bfloat16* __restrict__ Bt,
                                                 float* __restrict__ m1) {
  const int K = 1024;
  __shared__ __align__(16) __hip_bfloat16 Al[128 * 32];
  __shared__ __align__(16) __hip_bfloat16 Bl[96 * 32];
  const int tid = threadIdx.x;
  const int wid = tid >> 6, lane = tid & 63;
  const int wr = wid >> 1, wc = wid & 1;
  const int row0 = blockIdx.x * 128;
  const char* gsrc[4];
  char* ldst[4];
  bool act[4];
  #pragma unroll
  for (int i = 0; i < 4; ++i) {
    const int s = i * 4 + wid;
    act[i] = (s < 14);
    const int ss = act[i] ? s : 0;
    if (ss < 8) {
      const int r = ss * 16 + (lane >> 2);
      gsrc[i] = (const char*)(A + (size_t)(row0 + r) * K) + (lane & 3) * 16;
      ldst[i] = (char*)&Al[0] + ss * 1024;
    } else {
      const int r = (ss - 8) * 16 + (lane >> 2);
      gsrc[i] = (const char*)(Bt + (size_t)r * K) + (lane & 3) * 16;
      ldst[i] = (char*)&Bl[0] + (ss - 8) * 1024;
    }
  }
  f32x4 acc[4][3];
  #pragma unroll
  for (int i = 0; i < 4; ++i)
    #pragma unroll
    for (int j = 0; j < 3; ++j)
      acc[i][j] = (f32x4){0.f, 0.f, 0.f, 0.f};
  const int g = lane >> 4, m = lane & 15;
  for (int k0 = 0; k0 < K; k0 += 32) {
    #pragma unroll
    for (int i = 0; i < 4; ++i) if (act[i]) GLD(ldst[i], gsrc[i]);
    #pragma unroll
    for (int i = 0; i < 4; ++i) gsrc[i] += 64;
    __syncthreads();
    bf16x8 af[4], bfr[3];
    #pragma unroll
    for (int i = 0; i < 4; ++i)
      af[i] = *(const bf16x8*)&Al[(wr * 64 + i * 16 + m) * 32 + g * 8];
    #pragma unroll
    for (int j = 0; j < 3; ++j)
      bfr[j] = *(const bf16x8*)&Bl[(wc * 48 + j * 16 + m) * 32 + g * 8];
    #pragma unroll
    for (int i = 0; i < 4; ++i)
      #pragma unroll
      for (int j = 0; j < 3; ++j)
        acc[i][j] = __builtin_amdgcn_mfma_f32_16x16x32_bf16(af[i], bfr[j], acc[i][j], 0, 0, 0);
    __syncthreads();
  }
  #pragma unroll
  for (int i = 0; i < 4; ++i) {
    const int grow = row0 + wr * 64 + i * 16 + g * 4;
    #pragma unroll
    for (int j = 0; j < 3; ++j) {
      const int gcol = wc * 48 + j * 16 + m;
      #pragma unroll
      for (int e = 0; e < 4; ++e)
        m1[(size_t)(grow + e) * 96 + gcol] = tanhf(acc[i][j][e]);
    }
  }
}

// ---------------------------------------------------------------------------
// Kernel 3: mk/mv/mr = m1 @ w2[l] ; xk/xv/xr = x + xx*(maa_* + m*)  -> bf16
// ---------------------------------------------------------------------------
__global__ __launch_bounds__(256) void k_mix2(const float* __restrict__ x,
                                              const float* __restrict__ xx,
                                              const float* __restrict__ m1,
                                              const float* __restrict__ w2,
                                              const float* __restrict__ maa_k,
                                              const float* __restrict__ maa_v,
                                              const float* __restrict__ maa_r,
                                              __hip_bfloat16* __restrict__ xk,
                                              __hip_bfloat16* __restrict__ xv,
                                              __hip_bfloat16* __restrict__ xr) {
  __shared__ float sm[4 * 96];
  int tid = threadIdx.x;
  int tok0 = blockIdx.x * 4;
  for (int i = tid; i < 4 * 96; i += 256)
    sm[i] = m1[(size_t)tok0 * 96 + i];
  __syncthreads();
  for (int cc = 0; cc < 4; ++cc) {
    int c = tid + cc * 256;
    float a0[4] = {0.f,0.f,0.f,0.f};
    float a1[4] = {0.f,0.f,0.f,0.f};
    float a2[4] = {0.f,0.f,0.f,0.f};
    for (int d = 0; d < 32; ++d) {
      float w0 = w2[(size_t)(0 * 32 + d) * 1024 + c];
      float w1v = w2[(size_t)(1 * 32 + d) * 1024 + c];
      float w2v = w2[(size_t)(2 * 32 + d) * 1024 + c];
      #pragma unroll
      for (int tt = 0; tt < 4; ++tt) {
        a0[tt] = fmaf(sm[tt * 96 + d], w0, a0[tt]);
        a1[tt] = fmaf(sm[tt * 96 + 32 + d], w1v, a1[tt]);
        a2[tt] = fmaf(sm[tt * 96 + 64 + d], w2v, a2[tt]);
      }
    }
    float mak = maa_k[c], mav = maa_v[c], mar = maa_r[c];
    #pragma unroll
    for (int tt = 0; tt < 4; ++tt) {
      size_t off = (size_t)(tok0 + tt) * 1024 + c;
      float xval = x[off], xxv = xx[off];
      xk[off] = __float2bfloat16(fmaf(xxv, mak + a0[tt], xval));
      xv[off] = __float2bfloat16(fmaf(xxv, mav + a1[tt], xval));
      xr[off] = __float2bfloat16(fmaf(xxv, mar + a2[tt], xval));
    }
  }
}

// ---------------------------------------------------------------------------
// Convert+transpose: W (K x N, f32) -> Wt (N x K, bf16). grid (N/32, K/32).
// ---------------------------------------------------------------------------
__global__ __launch_bounds__(256) void k_cvt_t(const float* __restrict__ W,
                                               __hip_bfloat16* __restrict__ Wt,
                                               int K, int N) {
  __shared__ float tile[32][33];
  int n0 = blockIdx.x * 32, k0 = blockIdx.y * 32;
  int tid = threadIdx.x;
  int c = tid & 31, r = tid >> 5;   // r = 0..7
  #pragma unroll
  for (int i = 0; i < 4; ++i)
    tile[r + i * 8][c] = W[(size_t)(k0 + r + i * 8) * N + n0 + c];
  __syncthreads();
  #pragma unroll
  for (int i = 0; i < 4; ++i)
    Wt[(size_t)(n0 + r + i * 8) * K + k0 + c] = __float2bfloat16(tile[c][r + i * 8]);
}

// ---------------------------------------------------------------------------
// bf16 MFMA GEMM: C(f32) = A(M x K, bf16 row-major) @ Bt(N x K, bf16)^T
// Tile BM=128, BN=FN*32, BK=32. 4 waves (2x2), each 64 x BN/2.
// EPI: 0 plain, 1 exp(-exp(x))
// ---------------------------------------------------------------------------
template <int FN, int EPI>
__global__ __launch_bounds__(256) void k_gemm16(const __hip_bfloat16* __restrict__ A,
                                                const __hip_bfloat16* __restrict__ Bt,
                                                float* __restrict__ C,
                                                const int K, const int N) {
  constexpr int BN = FN * 32;
  constexpr int NISS = 8 + BN / 16;
  constexpr int PW = NISS / 4;
  __shared__ __align__(16) __hip_bfloat16 Al[128 * 32];
  __shared__ __align__(16) __hip_bfloat16 Bl[BN * 32];
  const int tid = threadIdx.x;
  const int wid = tid >> 6, lane = tid & 63;
  const int wr = wid >> 1, wc = wid & 1;
  const int row0 = blockIdx.y * 128, col0 = blockIdx.x * BN;
  const char* gsrc[PW];
  char* ldst[PW];
  #pragma unroll
  for (int i = 0; i < PW; ++i) {
    const int s = wid + i * 4;
    if (s < 8) {
      const int r = s * 16 + (lane >> 2);
      gsrc[i] = (const char*)(A + (size_t)(row0 + r) * K) + (lane & 3) * 16;
      ldst[i] = (char*)&Al[0] + s * 1024;
    } else {
      const int r = (s - 8) * 16 + (lane >> 2);
      gsrc[i] = (const char*)(Bt + (size_t)(col0 + r) * K) + (lane & 3) * 16;
      ldst[i] = (char*)&Bl[0] + (s - 8) * 1024;
    }
  }
  f32x4 acc[4][FN];
  #pragma unroll
  for (int i = 0; i < 4; ++i)
    #pragma unroll
    for (int j = 0; j < FN; ++j)
      acc[i][j] = (f32x4){0.f, 0.f, 0.f, 0.f};
  const int g = lane >> 4, m = lane & 15;
  for (int k0 = 0; k0 < K; k0 += 32) {
    #pragma unroll
    for (int i = 0; i < PW; ++i) GLD(ldst[i], gsrc[i]);
    #pragma unroll
    for (int i = 0; i < PW; ++i) gsrc[i] += 64;
    __syncthreads();
    bf16x8 af[4], bfr[FN];
    #pragma unroll
    for (int i = 0; i < 4; ++i)
      af[i] = *(const bf16x8*)&Al[(wr * 64 + i * 16 + m) * 32 + g * 8];
    #pragma unroll
    for (int j = 0; j < FN; ++j)
      bfr[j] = *(const bf16x8*)&Bl[(wc * (BN / 2) + j * 16 + m) * 32 + g * 8];
    #pragma unroll
    for (int i = 0; i < 4; ++i)
      #pragma unroll
      for (int j = 0; j < FN; ++j)
        acc[i][j] = __builtin_amdgcn_mfma_f32_16x16x32_bf16(af[i], bfr[j], acc[i][j], 0, 0, 0);
    __syncthreads();
  }
  #pragma unroll
  for (int i = 0; i < 4; ++i) {
    const int grow = row0 + wr * 64 + i * 16 + g * 4;
    #pragma unroll
    for (int j = 0; j < FN; ++j) {
      const int gcol = col0 + wc * (BN / 2) + j * 16 + m;
      #pragma unroll
      for (int e = 0; e < 4; ++e) {
        float val = acc[i][j][e];
        if (EPI == 1) val = expf(-expf(val));
        C[(size_t)(grow + e) * N + gcol] = val;
      }
    }
  }
}

// ---------------------------------------------------------------------------
// Fused Wvg GEMM: gated[r, c] = (A@B)[r,c] * silu((A@B)[r,c+3072])
// ---------------------------------------------------------------------------
__global__ __launch_bounds__(256) void k_gemm_vg16(const __hip_bfloat16* __restrict__ A,
                                                   const __hip_bfloat16* __restrict__ Bt,
                                                   float* __restrict__ v,
                                                   __hip_bfloat16* __restrict__ ffn) {
  const int K = 1024;
  __shared__ __align__(16) __hip_bfloat16 Al[128 * 32];
  __shared__ __align__(16) __hip_bfloat16 B1l[64 * 32];
  __shared__ __align__(16) __hip_bfloat16 B2l[64 * 32];
  const int tid = threadIdx.x;
  const int wid = tid >> 6, lane = tid & 63;
  const int wr = wid >> 1, wc = wid & 1;
  const int row0 = blockIdx.y * 128, col0 = blockIdx.x * 64;
  const char* gsrc[4];
  char* ldst[4];
  #pragma unroll
  for (int i = 0; i < 4; ++i) {
    const int s = wid + i * 4;
    if (s < 8) {
      const int r = s * 16 + (lane >> 2);
      gsrc[i] = (const char*)(A + (size_t)(row0 + r) * K) + (lane & 3) * 16;
      ldst[i] = (char*)&Al[0] + s * 1024;
    } else if (s < 12) {
      const int r = col0 + (s - 8) * 16 + (lane >> 2);
      gsrc[i] = (const char*)(Bt + (size_t)r * K) + (lane & 3) * 16;
      ldst[i] = (char*)&B1l[0] + (s - 8) * 1024;
    } else {
      const int r = 3072 + col0 + (s - 12) * 16 + (lane >> 2);
      gsrc[i] = (const char*)(Bt + (size_t)r * K) + (lane & 3) * 16;
      ldst[i] = (char*)&B2l[0] + (s - 12) * 1024;
    }
  }
  f32x4 a1[4][2], a2[4][2];
  #pragma unroll
  for (int i = 0; i < 4; ++i)
    #pragma unroll
    for (int j = 0; j < 2; ++j) {
      a1[i][j] = (f32x4){0.f, 0.f, 0.f, 0.f};
      a2[i][j] = (f32x4){0.f, 0.f, 0.f, 0.f};
    }
  const int g = lane >> 4, m = lane & 15;
  for (int k0 = 0; k0 < K; k0 += 32) {
    #pragma unroll
    for (int i = 0; i < 4; ++i) GLD(ldst[i], gsrc[i]);
    #pragma unroll
    for (int i = 0; i < 4; ++i) gsrc[i] += 64;
    __syncthreads();
    bf16x8 af[4], b1f[2], b2f[2];
    #pragma unroll
    for (int i = 0; i < 4; ++i)
      af[i] = *(const bf16x8*)&Al[(wr * 64 + i * 16 + m) * 32 + g * 8];
    #pragma unroll
    for (int j = 0; j < 2; ++j) {
      b1f[j] = *(const bf16x8*)&B1l[(wc * 32 + j * 16 + m) * 32 + g * 8];
      b2f[j] = *(const bf16x8*)&B2l[(wc * 32 + j * 16 + m) * 32 + g * 8];
    }
    #pragma unroll
    for (int i = 0; i < 4; ++i)
      #pragma unroll
      for (int j = 0; j < 2; ++j) {
        a1[i][j] = __builtin_amdgcn_mfma_f32_16x16x32_bf16(af[i], b1f[j], a1[i][j], 0, 0, 0);
        a2[i][j] = __builtin_amdgcn_mfma_f32_16x16x32_bf16(af[i], b2f[j], a2[i][j], 0, 0, 0);
      }
    __syncthreads();
  }
  const bool to_v = (col0 < 1024);
  #pragma unroll
  for (int i = 0; i < 4; ++i) {
    const int grow = row0 + wr * 64 + i * 16 + g * 4;
    #pragma unroll
    for (int j = 0; j < 2; ++j) {
      const int gcol = col0 + wc * 32 + j * 16 + m;
      #pragma unroll
      for (int e = 0; e < 4; ++e) {
        float gate = a2[i][j][e];
        float val = a1[i][j][e] * (gate / (1.f + expf(-gate)));
        if (to_v) v[(size_t)(grow + e) * 1024 + gcol] = val;
        else ffn[(size_t)(grow + e) * 2048 + (gcol - 1024)] = __float2bfloat16(val);
      }
    }
  }
}

// ---------------------------------------------------------------------------
// Final GEMM: out = [ln16 (4096x1024) | ffn16 (4096x2048)] @ Wo_t^T
// ---------------------------------------------------------------------------
__global__ __launch_bounds__(256) void k_gemm_wo16(const __hip_bfloat16* __restrict__ A1,
                                                   const __hip_bfloat16* __restrict__ A2,
                                                   const __hip_bfloat16* __restrict__ Bt,
                                                   float* __restrict__ C) {
  const int Kt = 3072;
  __shared__ __align__(16) __hip_bfloat16 Al[128 * 32];
  __shared__ __align__(16) __hip_bfloat16 Bl[64 * 32];
  const int tid = threadIdx.x;
  const int wid = tid >> 6, lane = tid & 63;
  const int wr = wid >> 1, wc = wid & 1;
  const int row0 = blockIdx.y * 128, col0 = blockIdx.x * 64;
  const char* gsrc[3];
  char* ldst[3];
  #pragma unroll
  for (int i = 0; i < 3; ++i) {
    const int s = wid + i * 4;
    if (s < 8) {
      const int r = s * 16 + (lane >> 2);
      gsrc[i] = (const char*)(A1 + (size_t)(row0 + r) * 1024) + (lane & 3) * 16;
      ldst[i] = (char*)&Al[0] + s * 1024;
    } else {
      const int r = col0 + (s - 8) * 16 + (lane >> 2);
      gsrc[i] = (const char*)(Bt + (size_t)r * Kt) + (lane & 3) * 16;
      ldst[i] = (char*)&Bl[0] + (s - 8) * 1024;
    }
  }
  f32x4 acc[4][2];
  #pragma unroll
  for (int i = 0; i < 4; ++i)
    #pragma unroll
    for (int j = 0; j < 2; ++j)
      acc[i][j] = (f32x4){0.f, 0.f, 0.f, 0.f};
  const int g = lane >> 4, m = lane & 15;

  #define WO_STEP() do {                                                          \
    _Pragma("unroll")                                                             \
    for (int i = 0; i < 3; ++i) GLD(ldst[i], gsrc[i]);                            \
    _Pragma("unroll")                                                             \
    for (int i = 0; i < 3; ++i) gsrc[i] += 64;                                    \
    __syncthreads();                                                              \
    bf16x8 af[4], bfr[2];                                                         \
    _Pragma("unroll")                                                             \
    for (int i = 0; i < 4; ++i)                                                   \
      af[i] = *(const bf16x8*)&Al[(wr * 64 + i * 16 + m) * 32 + g * 8];           \
    _Pragma("unroll")                                                             \
    for (int j = 0; j < 2; ++j)                                                   \
      bfr[j] = *(const bf16x8*)&Bl[(wc * 32 + j * 16 + m) * 32 + g * 8];          \
    _Pragma("unroll")                                                             \
    for (int i = 0; i < 4; ++i)                                                   \
      _Pragma("unroll")                                                           \
      for (int j = 0; j < 2; ++j)                                                 \
        acc[i][j] = __builtin_amdgcn_mfma_f32_16x16x32_bf16(af[i], bfr[j],        \
                                                            acc[i][j], 0, 0, 0); \
    __syncthreads();                                                              \
  } while (0)

  for (int k0 = 0; k0 < 1024; k0 += 32) WO_STEP();
  #pragma unroll
  for (int i = 0; i < 3; ++i) {
    const int s = wid + i * 4;
    if (s < 8) {
      const int r = s * 16 + (lane >> 2);
      gsrc[i] = (const char*)(A2 + (size_t)(row0 + r) * 2048) + (lane & 3) * 16;
    }
  }
  for (int k0 = 0; k0 < 2048; k0 += 32) WO_STEP();
  #undef WO_STEP

  #pragma unroll
  for (int i = 0; i < 4; ++i) {
    const int grow = row0 + wr * 64 + i * 16 + g * 4;
    #pragma unroll
    for (int j = 0; j < 2; ++j) {
      const int gcol = col0 + wc * 32 + j * 16 + m;
      #pragma unroll
      for (int e = 0; e < 4; ++e)
        C[(size_t)(grow + e) * 1024 + gcol] = acc[i][j][e];
    }
  }
}

// ---------------------------------------------------------------------------
// WKV6 phase 1: per-chunk local recurrence from S=0.
// ---------------------------------------------------------------------------
__global__ __launch_bounds__(256) void k_wkv1(const float* __restrict__ r,
                                              const float* __restrict__ e,
                                              const float* __restrict__ v,
                                              const float* __restrict__ u,
                                              float* __restrict__ o,
                                              float* __restrict__ Dcum,
                                              float* __restrict__ Dtot,
                                              float* __restrict__ Inc) {
  int blk = blockIdx.x;
  int c = blk & (NCn - 1);
  int bh = blk >> 4;
  int b = bh >> 4, h = bh & 15;
  int tid = threadIdx.x, wave = tid >> 6, lane = tid & 63;
  size_t base = (size_t)b * Tn * Cn + (size_t)h * 64 + (size_t)c * Ln * Cn;
  int jbase = wave * 16 + (lane & 15);
  float uv = u[h * 64 + jbase];
  float st[16];
  #pragma unroll
  for (int i = 0; i < 16; ++i) st[i] = 0.f;
  float cum = 1.f;
  __shared__ float yp[4][64];
  for (int t = 0; t < Ln; ++t) {
    size_t off = base + (size_t)t * Cn;
    float rv = r[off + jbase];
    float ev = e[off + jbase];
    float vv = v[off + lane];
    if (lane < 16) Dcum[off + jbase] = cum;
    cum *= ev;
    float y = 0.f;
    #pragma unroll
    for (int jj = 0; jj < 16; ++jj) {
      float rj = rdlane(rv, jj);
      float ej = rdlane(ev, jj);
      float uj = rdlane(uv, jj);
      float kv = (1.f - ej) * vv;       // k = 1 - e
      y = fmaf(rj, fmaf(uj, kv, st[jj]), y);
      st[jj] = fmaf(st[jj], ej, kv);
    }
    yp[wave][lane] = y;
    __syncthreads();
    if (wave == 0)
      o[off + lane] = yp[0][lane] + yp[1][lane] + yp[2][lane] + yp[3][lane];
    __syncthreads();
  }
  size_t sbase = ((size_t)bh * NCn + c) * 4096;
  #pragma unroll
  for (int jj = 0; jj < 16; ++jj)
    Inc[sbase + (size_t)(wave * 16 + jj) * 64 + lane] = st[jj];
  if (lane < 16)
    Dtot[((size_t)bh * NCn + c) * 64 + jbase] = cum;
}

// ---------------------------------------------------------------------------
// WKV6 phase 2: sequential combine of chunk states, in place.
// ---------------------------------------------------------------------------
__global__ __launch_bounds__(256) void k_wkv2(float* __restrict__ S,
                                              const float* __restrict__ Dtot) {
  int bh = blockIdx.x;
  int tid = threadIdx.x;
  float4 s[4];
  #pragma unroll
  for (int j = 0; j < 4; ++j) { s[j].x = 0.f; s[j].y = 0.f; s[j].z = 0.f; s[j].w = 0.f; }
  size_t sb = (size_t)bh * NCn * 4096;
  for (int c = 0; c < NCn; ++c) {
    float4* entry = (float4*)(S + sb + (size_t)c * 4096);
    const float* dt = Dtot + ((size_t)bh * NCn + c) * 64;
    #pragma unroll
    for (int j = 0; j < 4; ++j) {
      int idx4 = tid + j * 256;
      int k = idx4 >> 4;
      float d = dt[k];
      float4 inc = entry[idx4];
      float4 cur = s[j];
      entry[idx4] = cur;
      s[j].x = fmaf(cur.x, d, inc.x);
      s[j].y = fmaf(cur.y, d, inc.y);
      s[j].z = fmaf(cur.z, d, inc.z);
      s[j].w = fmaf(cur.w, d, inc.w);
    }
  }
}

// ---------------------------------------------------------------------------
// WKV6 phase 3: o_t += (r_t * Dcum_t) . S_start_{chunk(t)}
// ---------------------------------------------------------------------------
__global__ __launch_bounds__(256) void k_wkv3(const float* __restrict__ r,
                                              const float* __restrict__ Dcum,
                                              const float* __restrict__ S,
                                              float* __restrict__ o) {
  int blk = blockIdx.x;
  int c = blk & (NCn - 1);
  if (c == 0) return;
  int bh = blk >> 4;
  int b = bh >> 4, h = bh & 15;
  int tid = threadIdx.x, wave = tid >> 6, lane = tid & 63;
  const float* Sg = S + ((size_t)bh * NCn + c) * 4096;
  float sreg[64];
  #pragma unroll
  for (int k = 0; k < 64; ++k) sreg[k] = Sg[k * 64 + lane];
  size_t base = (size_t)b * Tn * Cn + (size_t)h * 64 + (size_t)c * Ln * Cn;
  for (int ti = 0; ti < 16; ++ti) {
    int t = wave * 16 + ti;
    size_t off = base + (size_t)t * Cn;
    float rd = r[off + lane] * Dcum[off + lane];
    float y = 0.f;
    #pragma unroll
    for (int k = 0; k < 64; ++k)
      y = fmaf(rdlane(rd, k), sreg[k], y);
    o[off + lane] += y;
  }
}

// ---------------------------------------------------------------------------
// LayerNorm over C=1024 -> ln16 (bf16 4096x1024)
// ---------------------------------------------------------------------------
__global__ __launch_bounds__(256) void k_ln(const float* __restrict__ o,
                                            const float* __restrict__ g,
                                            const float* __restrict__ bta,
                                            __hip_bfloat16* __restrict__ ln16) {
  int bt = blockIdx.x, tid = threadIdx.x;
  const float4* row = (const float4*)(o + (size_t)bt * 1024);
  float4 v = row[tid];
  float s = v.x + v.y + v.z + v.w;
  float s2 = fmaf(v.x, v.x, fmaf(v.y, v.y, fmaf(v.z, v.z, v.w * v.w)));
  #pragma unroll
  for (int m = 1; m < 64; m <<= 1) {
    s += __shfl_xor(s, m, 64);
    s2 += __shfl_xor(s2, m, 64);
  }
  __shared__ float rs[4], rq[4];
  if ((tid & 63) == 0) { rs[tid >> 6] = s; rq[tid >> 6] = s2; }
  __syncthreads();
  s = rs[0] + rs[1] + rs[2] + rs[3];
  s2 = rq[0] + rq[1] + rq[2] + rq[3];
  float mu = s * (1.f / 1024.f);
  float var = s2 * (1.f / 1024.f) - mu * mu;
  float rstd = rsqrtf(var + 1e-5f);
  float4 gv = ((const float4*)g)[tid];
  float4 bv = ((const float4*)bta)[tid];
  ushort4 outv;
  outv.x = bfbits(fmaf((v.x - mu) * rstd, gv.x, bv.x));
  outv.y = bfbits(fmaf((v.y - mu) * rstd, gv.y, bv.y));
  outv.z = bfbits(fmaf((v.z - mu) * rstd, gv.z, bv.z));
  outv.w = bfbits(fmaf((v.w - mu) * rstd, gv.w, bv.w));
  ((ushort4*)((unsigned short*)ln16 + (size_t)bt * 1024))[tid] = outv;
}

// ---------------------------------------------------------------------------
extern "C" void kernel_launch(void* const* d_in, const int* in_sizes, int n_in,
                              void* d_out, int out_size, void* d_ws, size_t ws_size,
                              hipStream_t stream) {
  const float* x     = (const float*)d_in[0];
  const float* maa_x = (const float*)d_in[1];
  const float* maa_k = (const float*)d_in[2];
  const float* maa_v = (const float*)d_in[3];
  const float* maa_r = (const float*)d_in[4];
  const float* w1    = (const float*)d_in[5];
  const float* w2    = (const float*)d_in[6];
  const float* u     = (const float*)d_in[7];
  const float* Wr    = (const float*)d_in[8];
  const float* Wk    = (const float*)d_in[9];
  const float* Wvg   = (const float*)d_in[10];
  const float* Wo    = (const float*)d_in[11];
  const float* ln_g  = (const float*)d_in[12];
  const float* ln_b  = (const float*)d_in[13];
  float* out = (float*)d_out;
  float* ws = (float*)d_ws;

  // Workspace layout (floats), total 36M floats = 144 MB.
  const size_t M1 = 1048576;
  float* xx    = ws;                        //  0   .. 4M   f32  -> oo
  __hip_bfloat16* xxx16 = (__hip_bfloat16*)(ws + 4 * M1);  // 4M..6M (bf16) -> rr slot
  float* m1    = ws + 8 * M1;               //  8M  .. +384K f32 -> Dtot
  __hip_bfloat16* w1t = (__hip_bfloat16*)(ws + 8 * M1 + 393216); // 96x1024 bf16 (48K fl)
  __hip_bfloat16* xk16 = (__hip_bfloat16*)(ws + 8 * M1 + 524288);   // 8.5M..10.5M
  __hip_bfloat16* xv16 = (__hip_bfloat16*)(ws + 10 * M1 + 524288);  // 10.5M..12.5M
  __hip_bfloat16* xr16 = (__hip_bfloat16*)(ws + 12 * M1 + 524288);  // 12.5M..14.5M
  float* ee    = ws + 14 * M1 + 524288;     // 14.5M..18.5M f32
  float* vv    = ws + 18 * M1 + 524288;     // 18.5M..22.5M f32
  float* Sbuf  = ws + 22 * M1 + 524288;     // 22.5M..26.5M f32 Inc/S_start -> ln16
  __hip_bfloat16* ffn16 = (__hip_bfloat16*)(ws + 26 * M1 + 524288); // 26.5M..30.5M
  __hip_bfloat16* Wr16t = (__hip_bfloat16*)(ws + 30 * M1 + 524288); // 0.5M floats
  __hip_bfloat16* Wk16t = (__hip_bfloat16*)(ws + 31 * M1);          // 0.5M floats
  __hip_bfloat16* Wvg16t = (__hip_bfloat16*)(ws + 31 * M1 + 524288);// 3M floats
  __hip_bfloat16* Wo16t = (__hip_bfloat16*)(ws + 34 * M1 + 524288); // 1.5M floats
  float* rr = ws + 4 * M1;                  // overlays xxx16 (dead after mix1)
  float* oo = xx;
  float* Dcum = ws + 8 * M1 + 524288;       // overlaps xk16/xv16 (dead by wkv1)
  float* Dtot = m1;
  __hip_bfloat16* ln16 = (__hip_bfloat16*)Sbuf;  // after wkv3

  // weight converts (B^T bf16)
  k_cvt_t<<<dim3(3, 32), 256, 0, stream>>>(w1, w1t, 1024, 96);
  k_cvt_t<<<dim3(32, 32), 256, 0, stream>>>(Wr, Wr16t, 1024, 1024);
  k_cvt_t<<<dim3(32, 32), 256, 0, stream>>>(Wk, Wk16t, 1024, 1024);
  k_cvt_t<<<dim3(192, 32), 256, 0, stream>>>(Wvg, Wvg16t, 1024, 6144);
  k_cvt_t<<<dim3(32, 96), 256, 0, stream>>>(Wo, Wo16t, 3072, 1024);

  k_prep<<<4096, 256, 0, stream>>>(x, maa_x, xx, xxx16);
  // m1 = tanh(xxx @ w1) via MFMA
  k_mix1_16<<<32, 256, 0, stream>>>(xxx16, w1t, m1);
  k_mix2<<<1024, 256, 0, stream>>>(x, xx, m1, w2, maa_k, maa_v, maa_r, xk16, xv16, xr16);
  // r = xr @ Wr (f32 out into xxx slot; xxx16 dead after mix1)
  k_gemm16<2, 0><<<dim3(16, 32), 256, 0, stream>>>(xr16, Wr16t, rr, 1024, 1024);
  // gated vg = xv @ Wvg -> v (f32) + ffn (bf16)
  k_gemm_vg16<<<dim3(48, 32), 256, 0, stream>>>(xv16, Wvg16t, vv, ffn16);
  // e = exp(-exp(xk @ Wk)) (f32)
  k_gemm16<2, 1><<<dim3(16, 32), 256, 0, stream>>>(xk16, Wk16t, ee, 1024, 1024);
  // WKV6 chunk-parallel scan
  k_wkv1<<<64 * NCn, 256, 0, stream>>>(rr, ee, vv, u, oo, Dcum, Dtot, Sbuf);
  k_wkv2<<<64, 256, 0, stream>>>(Sbuf, Dtot);
  k_wkv3<<<64 * NCn, 256, 0, stream>>>(rr, Dcum, Sbuf, oo);
  // LayerNorm -> bf16 (Sbuf slot, S dead after wkv3)
  k_ln<<<4096, 256, 0, stream>>>(oo, ln_g, ln_b, ln16);
  // out = [ln16 | ffn16] @ Wo
  k_gemm_wo16<<<dim3(16, 32), 256, 0, stream>>>(ln16, ffn16, Wo16t, out);
}

// Round 5
// 360.759 us; speedup vs baseline: 5.5771x; 1.1988x over previous
//
#include <hip/hip_runtime.h>
#include <hip/hip_bf16.h>
#include <math.h>

// Problem constants
#define Bn 4
#define Tn 1024
#define Cn 1024
#define Hn 16
#define Kn 64
#define DFn 2048
#define NCn 16      // WKV chunks
#define Ln 64       // chunk length (NCn*Ln == Tn)

typedef __bf16 bf16x8 __attribute__((ext_vector_type(8)));
typedef float f32x4 __attribute__((ext_vector_type(4)));

#define GLD(dst, src) \
  __builtin_amdgcn_global_load_lds((__attribute__((address_space(1))) const void*)(src), \
                                   (__attribute__((address_space(3))) void*)(dst), 16, 0, 0)

__device__ __forceinline__ float rdlane(float v, int l) {
  return __int_as_float(__builtin_amdgcn_readlane(__float_as_int(v), l));
}

__device__ __forceinline__ unsigned short bfbits(float f) {
  union { __hip_bfloat16 h; unsigned short u; } cv;
  cv.h = __float2bfloat16(f);
  return cv.u;
}

// ---------------------------------------------------------------------------
// Kernel 1: xx = shift(x) - x (f32) ; xxx = x + xx*maa_x (bf16, feeds mix1)
// ---------------------------------------------------------------------------
__global__ __launch_bounds__(256) void k_prep(const float* __restrict__ x,
                                              const float* __restrict__ maa_x,
                                              float* __restrict__ xx,
                                              __hip_bfloat16* __restrict__ xxx16) {
  int idx = blockIdx.x * 256 + threadIdx.x;
  int c4 = idx & 255;
  int bt = idx >> 8;
  int t = bt & (Tn - 1);
  const float4* x4 = (const float4*)x;
  float4 xv = x4[idx];
  float4 xp;
  if (t > 0) xp = x4[idx - 256];
  else { xp.x = 0.f; xp.y = 0.f; xp.z = 0.f; xp.w = 0.f; }
  float4 d;
  d.x = xp.x - xv.x; d.y = xp.y - xv.y; d.z = xp.z - xv.z; d.w = xp.w - xv.w;
  float4 m = ((const float4*)maa_x)[c4];
  ushort4 o;
  o.x = bfbits(fmaf(d.x, m.x, xv.x));
  o.y = bfbits(fmaf(d.y, m.y, xv.y));
  o.z = bfbits(fmaf(d.z, m.z, xv.z));
  o.w = bfbits(fmaf(d.w, m.w, xv.w));
  ((float4*)xx)[idx] = d;
  ((ushort4*)xxx16)[idx] = o;
}

// ---------------------------------------------------------------------------
// Kernel 2 (MFMA): m1 = tanh(xxx16 @ w1t^T)  -> bf16 (4096 x 96)
// ---------------------------------------------------------------------------
__global__ __launch_bounds__(256) void k_mix1_16(const __hip_bfloat16* __restrict__ A,
                                                 const __hip_bfloat16* __restrict__ Bt,
                                                 __hip_bfloat16* __restrict__ m1) {
  const int K = 1024;
  __shared__ __align__(16) __hip_bfloat16 Al[128 * 32];
  __shared__ __align__(16) __hip_bfloat16 Bl[96 * 32];
  const int tid = threadIdx.x;
  const int wid = tid >> 6, lane = tid & 63;
  const int wr = wid >> 1, wc = wid & 1;
  const int row0 = blockIdx.x * 128;
  const char* gsrc[4];
  char* ldst[4];
  bool act[4];
  #pragma unroll
  for (int i = 0; i < 4; ++i) {
    const int s = i * 4 + wid;
    act[i] = (s < 14);
    const int ss = act[i] ? s : 0;
    if (ss < 8) {
      const int r = ss * 16 + (lane >> 2);
      gsrc[i] = (const char*)(A + (size_t)(row0 + r) * K) + (lane & 3) * 16;
      ldst[i] = (char*)&Al[0] + ss * 1024;
    } else {
      const int r = (ss - 8) * 16 + (lane >> 2);
      gsrc[i] = (const char*)(Bt + (size_t)r * K) + (lane & 3) * 16;
      ldst[i] = (char*)&Bl[0] + (ss - 8) * 1024;
    }
  }
  f32x4 acc[4][3];
  #pragma unroll
  for (int i = 0; i < 4; ++i)
    #pragma unroll
    for (int j = 0; j < 3; ++j)
      acc[i][j] = (f32x4){0.f, 0.f, 0.f, 0.f};
  const int g = lane >> 4, m = lane & 15;
  for (int k0 = 0; k0 < K; k0 += 32) {
    #pragma unroll
    for (int i = 0; i < 4; ++i) if (act[i]) GLD(ldst[i], gsrc[i]);
    #pragma unroll
    for (int i = 0; i < 4; ++i) gsrc[i] += 64;
    __syncthreads();
    bf16x8 af[4], bfr[3];
    #pragma unroll
    for (int i = 0; i < 4; ++i)
      af[i] = *(const bf16x8*)&Al[(wr * 64 + i * 16 + m) * 32 + g * 8];
    #pragma unroll
    for (int j = 0; j < 3; ++j)
      bfr[j] = *(const bf16x8*)&Bl[(wc * 48 + j * 16 + m) * 32 + g * 8];
    #pragma unroll
    for (int i = 0; i < 4; ++i)
      #pragma unroll
      for (int j = 0; j < 3; ++j)
        acc[i][j] = __builtin_amdgcn_mfma_f32_16x16x32_bf16(af[i], bfr[j], acc[i][j], 0, 0, 0);
    __syncthreads();
  }
  #pragma unroll
  for (int i = 0; i < 4; ++i) {
    const int grow = row0 + wr * 64 + i * 16 + g * 4;
    #pragma unroll
    for (int j = 0; j < 3; ++j) {
      const int gcol = wc * 48 + j * 16 + m;
      #pragma unroll
      for (int e = 0; e < 4; ++e)
        m1[(size_t)(grow + e) * 96 + gcol] = __float2bfloat16(tanhf(acc[i][j][e]));
    }
  }
}

// ---------------------------------------------------------------------------
// Kernel 3 (MFMA, one-shot K): m_l = m1 @ w2t[l]^T (K=32 each), fused epilogue
//   xk/xv/xr = x + xx*(maa_* + m_l)  -> bf16
// Tile 128 rows x 64 cols; A-tile 128x96 staged whole; B: 3 x (64x32).
// ---------------------------------------------------------------------------
__global__ __launch_bounds__(256) void k_mix2_16(const __hip_bfloat16* __restrict__ m1,
                                                 const __hip_bfloat16* __restrict__ w2t,
                                                 const float* __restrict__ x,
                                                 const float* __restrict__ xx,
                                                 const float* __restrict__ maa_k,
                                                 const float* __restrict__ maa_v,
                                                 const float* __restrict__ maa_r,
                                                 __hip_bfloat16* __restrict__ xk,
                                                 __hip_bfloat16* __restrict__ xv,
                                                 __hip_bfloat16* __restrict__ xr) {
  __shared__ __align__(16) __hip_bfloat16 Al[128 * 96];     // 24 KB contiguous
  __shared__ __align__(16) __hip_bfloat16 Bl[3 * 64 * 32];  // 12 KB
  const int tid = threadIdx.x;
  const int wid = tid >> 6, lane = tid & 63;
  const int wr = wid >> 1, wc = wid & 1;
  const int row0 = blockIdx.y * 128, col0 = blockIdx.x * 64;
  // stage A: m1 rows row0..row0+127 are a contiguous 24 KB block
  {
    const char* abase = (const char*)(m1 + (size_t)row0 * 96) + lane * 16;
    #pragma unroll
    for (int i = 0; i < 6; ++i) {
      const int s = wid + i * 4;          // 0..23
      GLD((char*)&Al[0] + s * 1024, abase + s * 1024);
    }
  }
  // stage B: per l, w2t rows col0..col0+63 = contiguous 4 KB
  {
    const char* bbase = (const char*)w2t + (size_t)col0 * 64 + lane * 16;
    #pragma unroll
    for (int i = 0; i < 3; ++i) {
      const int s = wid + i * 4;          // 0..11
      const int l = s >> 2, q = s & 3;
      GLD((char*)&Bl[0] + s * 1024, bbase + (size_t)l * 65536 + q * 1024);
    }
  }
  __syncthreads();
  const int g = lane >> 4, m = lane & 15;
  f32x4 a0[4][2], a1[4][2], a2[4][2];
  #pragma unroll
  for (int i = 0; i < 4; ++i)
    #pragma unroll
    for (int j = 0; j < 2; ++j) {
      a0[i][j] = (f32x4){0.f,0.f,0.f,0.f};
      a1[i][j] = (f32x4){0.f,0.f,0.f,0.f};
      a2[i][j] = (f32x4){0.f,0.f,0.f,0.f};
    }
  #pragma unroll
  for (int l = 0; l < 3; ++l) {
    bf16x8 af[4], bfj[2];
    #pragma unroll
    for (int i = 0; i < 4; ++i)
      af[i] = *(const bf16x8*)&Al[(wr * 64 + i * 16 + m) * 96 + l * 32 + g * 8];
    #pragma unroll
    for (int j = 0; j < 2; ++j)
      bfj[j] = *(const bf16x8*)&Bl[(l * 64 + wc * 32 + j * 16 + m) * 32 + g * 8];
    #pragma unroll
    for (int i = 0; i < 4; ++i)
      #pragma unroll
      for (int j = 0; j < 2; ++j) {
        if (l == 0) a0[i][j] = __builtin_amdgcn_mfma_f32_16x16x32_bf16(af[i], bfj[j], a0[i][j], 0, 0, 0);
        if (l == 1) a1[i][j] = __builtin_amdgcn_mfma_f32_16x16x32_bf16(af[i], bfj[j], a1[i][j], 0, 0, 0);
        if (l == 2) a2[i][j] = __builtin_amdgcn_mfma_f32_16x16x32_bf16(af[i], bfj[j], a2[i][j], 0, 0, 0);
      }
  }
  #pragma unroll
  for (int i = 0; i < 4; ++i) {
    const int grow = row0 + wr * 64 + i * 16 + g * 4;
    #pragma unroll
    for (int j = 0; j < 2; ++j) {
      const int gcol = col0 + wc * 32 + j * 16 + m;
      const float mk_ = maa_k[gcol], mv_ = maa_v[gcol], mr_ = maa_r[gcol];
      #pragma unroll
      for (int e = 0; e < 4; ++e) {
        const size_t off = (size_t)(grow + e) * 1024 + gcol;
        const float xval = x[off], xxv = xx[off];
        xk[off] = __float2bfloat16(fmaf(xxv, mk_ + a0[i][j][e], xval));
        xv[off] = __float2bfloat16(fmaf(xxv, mv_ + a1[i][j][e], xval));
        xr[off] = __float2bfloat16(fmaf(xxv, mr_ + a2[i][j][e], xval));
      }
    }
  }
}

// ---------------------------------------------------------------------------
// Convert+transpose: W (K x N, f32) -> Wt (N x K, bf16). grid (N/32, K/32).
// ---------------------------------------------------------------------------
__global__ __launch_bounds__(256) void k_cvt_t(const float* __restrict__ W,
                                               __hip_bfloat16* __restrict__ Wt,
                                               int K, int N) {
  __shared__ float tile[32][33];
  int n0 = blockIdx.x * 32, k0 = blockIdx.y * 32;
  int tid = threadIdx.x;
  int c = tid & 31, r = tid >> 5;   // r = 0..7
  #pragma unroll
  for (int i = 0; i < 4; ++i)
    tile[r + i * 8][c] = W[(size_t)(k0 + r + i * 8) * N + n0 + c];
  __syncthreads();
  #pragma unroll
  for (int i = 0; i < 4; ++i)
    Wt[(size_t)(n0 + r + i * 8) * K + k0 + c] = __float2bfloat16(tile[c][r + i * 8]);
}

// ---------------------------------------------------------------------------
// bf16 MFMA GEMM: C(f32) = A(M x K, bf16 row-major) @ Bt(N x K, bf16)^T
// Tile BM=128, BN=FN*32, BK=32. 4 waves (2x2), each 64 x BN/2.
// EPI: 0 plain, 1 exp(-exp(x))
// ---------------------------------------------------------------------------
template <int FN, int EPI>
__global__ __launch_bounds__(256) void k_gemm16(const __hip_bfloat16* __restrict__ A,
                                                const __hip_bfloat16* __restrict__ Bt,
                                                float* __restrict__ C,
                                                const int K, const int N) {
  constexpr int BN = FN * 32;
  constexpr int NISS = 8 + BN / 16;
  constexpr int PW = NISS / 4;
  __shared__ __align__(16) __hip_bfloat16 Al[128 * 32];
  __shared__ __align__(16) __hip_bfloat16 Bl[BN * 32];
  const int tid = threadIdx.x;
  const int wid = tid >> 6, lane = tid & 63;
  const int wr = wid >> 1, wc = wid & 1;
  const int row0 = blockIdx.y * 128, col0 = blockIdx.x * BN;
  const char* gsrc[PW];
  char* ldst[PW];
  #pragma unroll
  for (int i = 0; i < PW; ++i) {
    const int s = wid + i * 4;
    if (s < 8) {
      const int r = s * 16 + (lane >> 2);
      gsrc[i] = (const char*)(A + (size_t)(row0 + r) * K) + (lane & 3) * 16;
      ldst[i] = (char*)&Al[0] + s * 1024;
    } else {
      const int r = (s - 8) * 16 + (lane >> 2);
      gsrc[i] = (const char*)(Bt + (size_t)(col0 + r) * K) + (lane & 3) * 16;
      ldst[i] = (char*)&Bl[0] + (s - 8) * 1024;
    }
  }
  f32x4 acc[4][FN];
  #pragma unroll
  for (int i = 0; i < 4; ++i)
    #pragma unroll
    for (int j = 0; j < FN; ++j)
      acc[i][j] = (f32x4){0.f, 0.f, 0.f, 0.f};
  const int g = lane >> 4, m = lane & 15;
  for (int k0 = 0; k0 < K; k0 += 32) {
    #pragma unroll
    for (int i = 0; i < PW; ++i) GLD(ldst[i], gsrc[i]);
    #pragma unroll
    for (int i = 0; i < PW; ++i) gsrc[i] += 64;
    __syncthreads();
    bf16x8 af[4], bfr[FN];
    #pragma unroll
    for (int i = 0; i < 4; ++i)
      af[i] = *(const bf16x8*)&Al[(wr * 64 + i * 16 + m) * 32 + g * 8];
    #pragma unroll
    for (int j = 0; j < FN; ++j)
      bfr[j] = *(const bf16x8*)&Bl[(wc * (BN / 2) + j * 16 + m) * 32 + g * 8];
    #pragma unroll
    for (int i = 0; i < 4; ++i)
      #pragma unroll
      for (int j = 0; j < FN; ++j)
        acc[i][j] = __builtin_amdgcn_mfma_f32_16x16x32_bf16(af[i], bfr[j], acc[i][j], 0, 0, 0);
    __syncthreads();
  }
  #pragma unroll
  for (int i = 0; i < 4; ++i) {
    const int grow = row0 + wr * 64 + i * 16 + g * 4;
    #pragma unroll
    for (int j = 0; j < FN; ++j) {
      const int gcol = col0 + wc * (BN / 2) + j * 16 + m;
      #pragma unroll
      for (int e = 0; e < 4; ++e) {
        float val = acc[i][j][e];
        if (EPI == 1) val = expf(-expf(val));
        C[(size_t)(grow + e) * N + gcol] = val;
      }
    }
  }
}

// ---------------------------------------------------------------------------
// Fused Wvg GEMM: gated[r, c] = (A@B)[r,c] * silu((A@B)[r,c+3072])
// ---------------------------------------------------------------------------
__global__ __launch_bounds__(256) void k_gemm_vg16(const __hip_bfloat16* __restrict__ A,
                                                   const __hip_bfloat16* __restrict__ Bt,
                                                   float* __restrict__ v,
                                                   __hip_bfloat16* __restrict__ ffn) {
  const int K = 1024;
  __shared__ __align__(16) __hip_bfloat16 Al[128 * 32];
  __shared__ __align__(16) __hip_bfloat16 B1l[64 * 32];
  __shared__ __align__(16) __hip_bfloat16 B2l[64 * 32];
  const int tid = threadIdx.x;
  const int wid = tid >> 6, lane = tid & 63;
  const int wr = wid >> 1, wc = wid & 1;
  const int row0 = blockIdx.y * 128, col0 = blockIdx.x * 64;
  const char* gsrc[4];
  char* ldst[4];
  #pragma unroll
  for (int i = 0; i < 4; ++i) {
    const int s = wid + i * 4;
    if (s < 8) {
      const int r = s * 16 + (lane >> 2);
      gsrc[i] = (const char*)(A + (size_t)(row0 + r) * K) + (lane & 3) * 16;
      ldst[i] = (char*)&Al[0] + s * 1024;
    } else if (s < 12) {
      const int r = col0 + (s - 8) * 16 + (lane >> 2);
      gsrc[i] = (const char*)(Bt + (size_t)r * K) + (lane & 3) * 16;
      ldst[i] = (char*)&B1l[0] + (s - 8) * 1024;
    } else {
      const int r = 3072 + col0 + (s - 12) * 16 + (lane >> 2);
      gsrc[i] = (const char*)(Bt + (size_t)r * K) + (lane & 3) * 16;
      ldst[i] = (char*)&B2l[0] + (s - 12) * 1024;
    }
  }
  f32x4 a1[4][2], a2[4][2];
  #pragma unroll
  for (int i = 0; i < 4; ++i)
    #pragma unroll
    for (int j = 0; j < 2; ++j) {
      a1[i][j] = (f32x4){0.f, 0.f, 0.f, 0.f};
      a2[i][j] = (f32x4){0.f, 0.f, 0.f, 0.f};
    }
  const int g = lane >> 4, m = lane & 15;
  for (int k0 = 0; k0 < K; k0 += 32) {
    #pragma unroll
    for (int i = 0; i < 4; ++i) GLD(ldst[i], gsrc[i]);
    #pragma unroll
    for (int i = 0; i < 4; ++i) gsrc[i] += 64;
    __syncthreads();
    bf16x8 af[4], b1f[2], b2f[2];
    #pragma unroll
    for (int i = 0; i < 4; ++i)
      af[i] = *(const bf16x8*)&Al[(wr * 64 + i * 16 + m) * 32 + g * 8];
    #pragma unroll
    for (int j = 0; j < 2; ++j) {
      b1f[j] = *(const bf16x8*)&B1l[(wc * 32 + j * 16 + m) * 32 + g * 8];
      b2f[j] = *(const bf16x8*)&B2l[(wc * 32 + j * 16 + m) * 32 + g * 8];
    }
    #pragma unroll
    for (int i = 0; i < 4; ++i)
      #pragma unroll
      for (int j = 0; j < 2; ++j) {
        a1[i][j] = __builtin_amdgcn_mfma_f32_16x16x32_bf16(af[i], b1f[j], a1[i][j], 0, 0, 0);
        a2[i][j] = __builtin_amdgcn_mfma_f32_16x16x32_bf16(af[i], b2f[j], a2[i][j], 0, 0, 0);
      }
    __syncthreads();
  }
  const bool to_v = (col0 < 1024);
  #pragma unroll
  for (int i = 0; i < 4; ++i) {
    const int grow = row0 + wr * 64 + i * 16 + g * 4;
    #pragma unroll
    for (int j = 0; j < 2; ++j) {
      const int gcol = col0 + wc * 32 + j * 16 + m;
      #pragma unroll
      for (int e = 0; e < 4; ++e) {
        float gate = a2[i][j][e];
        float val = a1[i][j][e] * (gate / (1.f + expf(-gate)));
        if (to_v) v[(size_t)(grow + e) * 1024 + gcol] = val;
        else ffn[(size_t)(grow + e) * 2048 + (gcol - 1024)] = __float2bfloat16(val);
      }
    }
  }
}

// ---------------------------------------------------------------------------
// Final GEMM: out = [ln16 (4096x1024) | ffn16 (4096x2048)] @ Wo_t^T
// ---------------------------------------------------------------------------
__global__ __launch_bounds__(256) void k_gemm_wo16(const __hip_bfloat16* __restrict__ A1,
                                                   const __hip_bfloat16* __restrict__ A2,
                                                   const __hip_bfloat16* __restrict__ Bt,
                                                   float* __restrict__ C) {
  const int Kt = 3072;
  __shared__ __align__(16) __hip_bfloat16 Al[128 * 32];
  __shared__ __align__(16) __hip_bfloat16 Bl[64 * 32];
  const int tid = threadIdx.x;
  const int wid = tid >> 6, lane = tid & 63;
  const int wr = wid >> 1, wc = wid & 1;
  const int row0 = blockIdx.y * 128, col0 = blockIdx.x * 64;
  const char* gsrc[3];
  char* ldst[3];
  #pragma unroll
  for (int i = 0; i < 3; ++i) {
    const int s = wid + i * 4;
    if (s < 8) {
      const int r = s * 16 + (lane >> 2);
      gsrc[i] = (const char*)(A1 + (size_t)(row0 + r) * 1024) + (lane & 3) * 16;
      ldst[i] = (char*)&Al[0] + s * 1024;
    } else {
      const int r = col0 + (s - 8) * 16 + (lane >> 2);
      gsrc[i] = (const char*)(Bt + (size_t)r * Kt) + (lane & 3) * 16;
      ldst[i] = (char*)&Bl[0] + (s - 8) * 1024;
    }
  }
  f32x4 acc[4][2];
  #pragma unroll
  for (int i = 0; i < 4; ++i)
    #pragma unroll
    for (int j = 0; j < 2; ++j)
      acc[i][j] = (f32x4){0.f, 0.f, 0.f, 0.f};
  const int g = lane >> 4, m = lane & 15;

  #define WO_STEP() do {                                                          \
    _Pragma("unroll")                                                             \
    for (int i = 0; i < 3; ++i) GLD(ldst[i], gsrc[i]);                            \
    _Pragma("unroll")                                                             \
    for (int i = 0; i < 3; ++i) gsrc[i] += 64;                                    \
    __syncthreads();                                                              \
    bf16x8 af[4], bfr[2];                                                         \
    _Pragma("unroll")                                                             \
    for (int i = 0; i < 4; ++i)                                                   \
      af[i] = *(const bf16x8*)&Al[(wr * 64 + i * 16 + m) * 32 + g * 8];           \
    _Pragma("unroll")                                                             \
    for (int j = 0; j < 2; ++j)                                                   \
      bfr[j] = *(const bf16x8*)&Bl[(wc * 32 + j * 16 + m) * 32 + g * 8];          \
    _Pragma("unroll")                                                             \
    for (int i = 0; i < 4; ++i)                                                   \
      _Pragma("unroll")                                                           \
      for (int j = 0; j < 2; ++j)                                                 \
        acc[i][j] = __builtin_amdgcn_mfma_f32_16x16x32_bf16(af[i], bfr[j],        \
                                                            acc[i][j], 0, 0, 0); \
    __syncthreads();                                                              \
  } while (0)

  for (int k0 = 0; k0 < 1024; k0 += 32) WO_STEP();
  #pragma unroll
  for (int i = 0; i < 3; ++i) {
    const int s = wid + i * 4;
    if (s < 8) {
      const int r = s * 16 + (lane >> 2);
      gsrc[i] = (const char*)(A2 + (size_t)(row0 + r) * 2048) + (lane & 3) * 16;
    }
  }
  for (int k0 = 0; k0 < 2048; k0 += 32) WO_STEP();
  #undef WO_STEP

  #pragma unroll
  for (int i = 0; i < 4; ++i) {
    const int grow = row0 + wr * 64 + i * 16 + g * 4;
    #pragma unroll
    for (int j = 0; j < 2; ++j) {
      const int gcol = col0 + wc * 32 + j * 16 + m;
      #pragma unroll
      for (int e = 0; e < 4; ++e)
        C[(size_t)(grow + e) * 1024 + gcol] = acc[i][j][e];
    }
  }
}

// ---------------------------------------------------------------------------
// WKV6 phase 1: per-chunk local recurrence from S=0.
// ---------------------------------------------------------------------------
__global__ __launch_bounds__(256) void k_wkv1(const float* __restrict__ r,
                                              const float* __restrict__ e,
                                              const float* __restrict__ v,
                                              const float* __restrict__ u,
                                              float* __restrict__ o,
                                              float* __restrict__ Dcum,
                                              float* __restrict__ Dtot,
                                              float* __restrict__ Inc) {
  int blk = blockIdx.x;
  int c = blk & (NCn - 1);
  int bh = blk >> 4;
  int b = bh >> 4, h = bh & 15;
  int tid = threadIdx.x, wave = tid >> 6, lane = tid & 63;
  size_t base = (size_t)b * Tn * Cn + (size_t)h * 64 + (size_t)c * Ln * Cn;
  int jbase = wave * 16 + (lane & 15);
  float uv = u[h * 64 + jbase];
  float st[16];
  #pragma unroll
  for (int i = 0; i < 16; ++i) st[i] = 0.f;
  float cum = 1.f;
  __shared__ float yp[4][64];
  for (int t = 0; t < Ln; ++t) {
    size_t off = base + (size_t)t * Cn;
    float rv = r[off + jbase];
    float ev = e[off + jbase];
    float vv = v[off + lane];
    if (lane < 16) Dcum[off + jbase] = cum;
    cum *= ev;
    float y = 0.f;
    #pragma unroll
    for (int jj = 0; jj < 16; ++jj) {
      float rj = rdlane(rv, jj);
      float ej = rdlane(ev, jj);
      float uj = rdlane(uv, jj);
      float kv = (1.f - ej) * vv;       // k = 1 - e
      y = fmaf(rj, fmaf(uj, kv, st[jj]), y);
      st[jj] = fmaf(st[jj], ej, kv);
    }
    yp[wave][lane] = y;
    __syncthreads();
    if (wave == 0)
      o[off + lane] = yp[0][lane] + yp[1][lane] + yp[2][lane] + yp[3][lane];
    __syncthreads();
  }
  size_t sbase = ((size_t)bh * NCn + c) * 4096;
  #pragma unroll
  for (int jj = 0; jj < 16; ++jj)
    Inc[sbase + (size_t)(wave * 16 + jj) * 64 + lane] = st[jj];
  if (lane < 16)
    Dtot[((size_t)bh * NCn + c) * 64 + jbase] = cum;
}

// ---------------------------------------------------------------------------
// WKV6 phase 2: sequential combine of chunk states, in place.
// ---------------------------------------------------------------------------
__global__ __launch_bounds__(256) void k_wkv2(float* __restrict__ S,
                                              const float* __restrict__ Dtot) {
  int bh = blockIdx.x;
  int tid = threadIdx.x;
  float4 s[4];
  #pragma unroll
  for (int j = 0; j < 4; ++j) { s[j].x = 0.f; s[j].y = 0.f; s[j].z = 0.f; s[j].w = 0.f; }
  size_t sb = (size_t)bh * NCn * 4096;
  for (int c = 0; c < NCn; ++c) {
    float4* entry = (float4*)(S + sb + (size_t)c * 4096);
    const float* dt = Dtot + ((size_t)bh * NCn + c) * 64;
    #pragma unroll
    for (int j = 0; j < 4; ++j) {
      int idx4 = tid + j * 256;
      int k = idx4 >> 4;
      float d = dt[k];
      float4 inc = entry[idx4];
      float4 cur = s[j];
      entry[idx4] = cur;
      s[j].x = fmaf(cur.x, d, inc.x);
      s[j].y = fmaf(cur.y, d, inc.y);
      s[j].z = fmaf(cur.z, d, inc.z);
      s[j].w = fmaf(cur.w, d, inc.w);
    }
  }
}

// ---------------------------------------------------------------------------
// WKV6 phase 3: o_t += (r_t * Dcum_t) . S_start_{chunk(t)}
// ---------------------------------------------------------------------------
__global__ __launch_bounds__(256) void k_wkv3(const float* __restrict__ r,
                                              const float* __restrict__ Dcum,
                                              const float* __restrict__ S,
                                              float* __restrict__ o) {
  int blk = blockIdx.x;
  int c = blk & (NCn - 1);
  if (c == 0) return;
  int bh = blk >> 4;
  int b = bh >> 4, h = bh & 15;
  int tid = threadIdx.x, wave = tid >> 6, lane = tid & 63;
  const float* Sg = S + ((size_t)bh * NCn + c) * 4096;
  float sreg[64];
  #pragma unroll
  for (int k = 0; k < 64; ++k) sreg[k] = Sg[k * 64 + lane];
  size_t base = (size_t)b * Tn * Cn + (size_t)h * 64 + (size_t)c * Ln * Cn;
  for (int ti = 0; ti < 16; ++ti) {
    int t = wave * 16 + ti;
    size_t off = base + (size_t)t * Cn;
    float rd = r[off + lane] * Dcum[off + lane];
    float y = 0.f;
    #pragma unroll
    for (int k = 0; k < 64; ++k)
      y = fmaf(rdlane(rd, k), sreg[k], y);
    o[off + lane] += y;
  }
}

// ---------------------------------------------------------------------------
// LayerNorm over C=1024 -> ln16 (bf16 4096x1024)
// ---------------------------------------------------------------------------
__global__ __launch_bounds__(256) void k_ln(const float* __restrict__ o,
                                            const float* __restrict__ g,
                                            const float* __restrict__ bta,
                                            __hip_bfloat16* __restrict__ ln16) {
  int bt = blockIdx.x, tid = threadIdx.x;
  const float4* row = (const float4*)(o + (size_t)bt * 1024);
  float4 v = row[tid];
  float s = v.x + v.y + v.z + v.w;
  float s2 = fmaf(v.x, v.x, fmaf(v.y, v.y, fmaf(v.z, v.z, v.w * v.w)));
  #pragma unroll
  for (int m = 1; m < 64; m <<= 1) {
    s += __shfl_xor(s, m, 64);
    s2 += __shfl_xor(s2, m, 64);
  }
  __shared__ float rs[4], rq[4];
  if ((tid & 63) == 0) { rs[tid >> 6] = s; rq[tid >> 6] = s2; }
  __syncthreads();
  s = rs[0] + rs[1] + rs[2] + rs[3];
  s2 = rq[0] + rq[1] + rq[2] + rq[3];
  float mu = s * (1.f / 1024.f);
  float var = s2 * (1.f / 1024.f) - mu * mu;
  float rstd = rsqrtf(var + 1e-5f);
  float4 gv = ((const float4*)g)[tid];
  float4 bv = ((const float4*)bta)[tid];
  ushort4 outv;
  outv.x = bfbits(fmaf((v.x - mu) * rstd, gv.x, bv.x));
  outv.y = bfbits(fmaf((v.y - mu) * rstd, gv.y, bv.y));
  outv.z = bfbits(fmaf((v.z - mu) * rstd, gv.z, bv.z));
  outv.w = bfbits(fmaf((v.w - mu) * rstd, gv.w, bv.w));
  ((ushort4*)((unsigned short*)ln16 + (size_t)bt * 1024))[tid] = outv;
}

// ---------------------------------------------------------------------------
extern "C" void kernel_launch(void* const* d_in, const int* in_sizes, int n_in,
                              void* d_out, int out_size, void* d_ws, size_t ws_size,
                              hipStream_t stream) {
  const float* x     = (const float*)d_in[0];
  const float* maa_x = (const float*)d_in[1];
  const float* maa_k = (const float*)d_in[2];
  const float* maa_v = (const float*)d_in[3];
  const float* maa_r = (const float*)d_in[4];
  const float* w1    = (const float*)d_in[5];
  const float* w2    = (const float*)d_in[6];
  const float* u     = (const float*)d_in[7];
  const float* Wr    = (const float*)d_in[8];
  const float* Wk    = (const float*)d_in[9];
  const float* Wvg   = (const float*)d_in[10];
  const float* Wo    = (const float*)d_in[11];
  const float* ln_g  = (const float*)d_in[12];
  const float* ln_b  = (const float*)d_in[13];
  float* out = (float*)d_out;
  float* ws = (float*)d_ws;

  // Workspace layout (floats), total 36M floats = 144 MB.
  const size_t M1 = 1048576;
  float* xx    = ws;                        //  0   .. 4M   f32  -> oo
  __hip_bfloat16* xxx16 = (__hip_bfloat16*)(ws + 4 * M1);  // 4M..6M (bf16) -> rr slot
  __hip_bfloat16* m1_16 = (__hip_bfloat16*)(ws + 8 * M1);  // 4096x96 bf16 -> Dtot
  __hip_bfloat16* w1t = (__hip_bfloat16*)(ws + 8 * M1 + 393216); // 96x1024 bf16
  __hip_bfloat16* w2t = (__hip_bfloat16*)(ws + 8 * M1 + 442368); // 3x1024x32 bf16
  __hip_bfloat16* xk16 = (__hip_bfloat16*)(ws + 8 * M1 + 524288);   // 8.5M..10.5M
  __hip_bfloat16* xv16 = (__hip_bfloat16*)(ws + 10 * M1 + 524288);  // 10.5M..12.5M
  __hip_bfloat16* xr16 = (__hip_bfloat16*)(ws + 12 * M1 + 524288);  // 12.5M..14.5M
  float* ee    = ws + 14 * M1 + 524288;     // 14.5M..18.5M f32
  float* vv    = ws + 18 * M1 + 524288;     // 18.5M..22.5M f32
  float* Sbuf  = ws + 22 * M1 + 524288;     // 22.5M..26.5M f32 Inc/S_start -> ln16
  __hip_bfloat16* ffn16 = (__hip_bfloat16*)(ws + 26 * M1 + 524288); // 26.5M..30.5M
  __hip_bfloat16* Wr16t = (__hip_bfloat16*)(ws + 30 * M1 + 524288); // 0.5M floats
  __hip_bfloat16* Wk16t = (__hip_bfloat16*)(ws + 31 * M1);          // 0.5M floats
  __hip_bfloat16* Wvg16t = (__hip_bfloat16*)(ws + 31 * M1 + 524288);// 3M floats
  __hip_bfloat16* Wo16t = (__hip_bfloat16*)(ws + 34 * M1 + 524288); // 1.5M floats
  float* rr = ws + 4 * M1;                  // overlays xxx16 (dead after mix1)
  float* oo = xx;
  float* Dcum = ws + 8 * M1 + 524288;       // overlaps xk16/xv16 (dead by wkv1)
  float* Dtot = (float*)m1_16;              // m1 dead after mix2
  __hip_bfloat16* ln16 = (__hip_bfloat16*)Sbuf;  // after wkv3

  // weight converts (B^T bf16)
  k_cvt_t<<<dim3(3, 32), 256, 0, stream>>>(w1, w1t, 1024, 96);
  k_cvt_t<<<dim3(32, 1), 256, 0, stream>>>(w2,           w2t,           32, 1024);
  k_cvt_t<<<dim3(32, 1), 256, 0, stream>>>(w2 + 32768,   w2t + 32768,   32, 1024);
  k_cvt_t<<<dim3(32, 1), 256, 0, stream>>>(w2 + 65536,   w2t + 65536,   32, 1024);
  k_cvt_t<<<dim3(32, 32), 256, 0, stream>>>(Wr, Wr16t, 1024, 1024);
  k_cvt_t<<<dim3(32, 32), 256, 0, stream>>>(Wk, Wk16t, 1024, 1024);
  k_cvt_t<<<dim3(192, 32), 256, 0, stream>>>(Wvg, Wvg16t, 1024, 6144);
  k_cvt_t<<<dim3(32, 96), 256, 0, stream>>>(Wo, Wo16t, 3072, 1024);

  k_prep<<<4096, 256, 0, stream>>>(x, maa_x, xx, xxx16);
  // m1 = tanh(xxx @ w1) via MFMA (bf16 out)
  k_mix1_16<<<32, 256, 0, stream>>>(xxx16, w1t, m1_16);
  // fused m2 GEMM + token-mix epilogue -> xk/xv/xr bf16
  k_mix2_16<<<dim3(16, 32), 256, 0, stream>>>(m1_16, w2t, x, xx, maa_k, maa_v, maa_r,
                                              xk16, xv16, xr16);
  // r = xr @ Wr (f32 out into xxx slot; xxx16 dead after mix1)
  k_gemm16<2, 0><<<dim3(16, 32), 256, 0, stream>>>(xr16, Wr16t, rr, 1024, 1024);
  // gated vg = xv @ Wvg -> v (f32) + ffn (bf16)
  k_gemm_vg16<<<dim3(48, 32), 256, 0, stream>>>(xv16, Wvg16t, vv, ffn16);
  // e = exp(-exp(xk @ Wk)) (f32)
  k_gemm16<2, 1><<<dim3(16, 32), 256, 0, stream>>>(xk16, Wk16t, ee, 1024, 1024);
  // WKV6 chunk-parallel scan
  k_wkv1<<<64 * NCn, 256, 0, stream>>>(rr, ee, vv, u, oo, Dcum, Dtot, Sbuf);
  k_wkv2<<<64, 256, 0, stream>>>(Sbuf, Dtot);
  k_wkv3<<<64 * NCn, 256, 0, stream>>>(rr, Dcum, Sbuf, oo);
  // LayerNorm -> bf16 (Sbuf slot, S dead after wkv3)
  k_ln<<<4096, 256, 0, stream>>>(oo, ln_g, ln_b, ln16);
  // out = [ln16 | ffn16] @ Wo
  k_gemm_wo16<<<dim3(16, 32), 256, 0, stream>>>(ln16, ffn16, Wo16t, out);
}

// Round 6
// 338.965 us; speedup vs baseline: 5.9357x; 1.0643x over previous
//
#include <hip/hip_runtime.h>
#include <hip/hip_bf16.h>
#include <math.h>

// Problem constants
#define Bn 4
#define Tn 1024
#define Cn 1024
#define Hn 16
#define Kn 64
#define DFn 2048
#define NCn 16      // WKV chunks
#define Ln 64       // chunk length (NCn*Ln == Tn)

typedef __bf16 bf16x8 __attribute__((ext_vector_type(8)));
typedef float f32x4 __attribute__((ext_vector_type(4)));

#define GLD(dst, src) \
  __builtin_amdgcn_global_load_lds((__attribute__((address_space(1))) const void*)(src), \
                                   (__attribute__((address_space(3))) void*)(dst), 16, 0, 0)

__device__ __forceinline__ float rdlane(float v, int l) {
  return __int_as_float(__builtin_amdgcn_readlane(__float_as_int(v), l));
}

__device__ __forceinline__ unsigned short bfbits(float f) {
  union { __hip_bfloat16 h; unsigned short u; } cv;
  cv.h = __float2bfloat16(f);
  return cv.u;
}

// ---------------------------------------------------------------------------
// Kernel 1: xx = shift(x) - x (f32) ; xxx = x + xx*maa_x (bf16, feeds mix1)
// ---------------------------------------------------------------------------
__global__ __launch_bounds__(256) void k_prep(const float* __restrict__ x,
                                              const float* __restrict__ maa_x,
                                              float* __restrict__ xx,
                                              __hip_bfloat16* __restrict__ xxx16) {
  int idx = blockIdx.x * 256 + threadIdx.x;
  int c4 = idx & 255;
  int bt = idx >> 8;
  int t = bt & (Tn - 1);
  const float4* x4 = (const float4*)x;
  float4 xv = x4[idx];
  float4 xp;
  if (t > 0) xp = x4[idx - 256];
  else { xp.x = 0.f; xp.y = 0.f; xp.z = 0.f; xp.w = 0.f; }
  float4 d;
  d.x = xp.x - xv.x; d.y = xp.y - xv.y; d.z = xp.z - xv.z; d.w = xp.w - xv.w;
  float4 m = ((const float4*)maa_x)[c4];
  ushort4 o;
  o.x = bfbits(fmaf(d.x, m.x, xv.x));
  o.y = bfbits(fmaf(d.y, m.y, xv.y));
  o.z = bfbits(fmaf(d.z, m.z, xv.z));
  o.w = bfbits(fmaf(d.w, m.w, xv.w));
  ((float4*)xx)[idx] = d;
  ((ushort4*)xxx16)[idx] = o;
}

// ---------------------------------------------------------------------------
// Kernel 2 (MFMA): m1 = tanh(xxx16 @ w1t^T)  -> bf16 (4096 x 96)
// ---------------------------------------------------------------------------
__global__ __launch_bounds__(256) void k_mix1_16(const __hip_bfloat16* __restrict__ A,
                                                 const __hip_bfloat16* __restrict__ Bt,
                                                 __hip_bfloat16* __restrict__ m1) {
  const int K = 1024;
  __shared__ __align__(16) __hip_bfloat16 Al[128 * 32];
  __shared__ __align__(16) __hip_bfloat16 Bl[96 * 32];
  const int tid = threadIdx.x;
  const int wid = tid >> 6, lane = tid & 63;
  const int wr = wid >> 1, wc = wid & 1;
  const int row0 = blockIdx.x * 128;
  const char* gsrc[4];
  char* ldst[4];
  bool act[4];
  #pragma unroll
  for (int i = 0; i < 4; ++i) {
    const int s = i * 4 + wid;
    act[i] = (s < 14);
    const int ss = act[i] ? s : 0;
    if (ss < 8) {
      const int r = ss * 16 + (lane >> 2);
      gsrc[i] = (const char*)(A + (size_t)(row0 + r) * K) + (lane & 3) * 16;
      ldst[i] = (char*)&Al[0] + ss * 1024;
    } else {
      const int r = (ss - 8) * 16 + (lane >> 2);
      gsrc[i] = (const char*)(Bt + (size_t)r * K) + (lane & 3) * 16;
      ldst[i] = (char*)&Bl[0] + (ss - 8) * 1024;
    }
  }
  f32x4 acc[4][3];
  #pragma unroll
  for (int i = 0; i < 4; ++i)
    #pragma unroll
    for (int j = 0; j < 3; ++j)
      acc[i][j] = (f32x4){0.f, 0.f, 0.f, 0.f};
  const int g = lane >> 4, m = lane & 15;
  for (int k0 = 0; k0 < K; k0 += 32) {
    #pragma unroll
    for (int i = 0; i < 4; ++i) if (act[i]) GLD(ldst[i], gsrc[i]);
    #pragma unroll
    for (int i = 0; i < 4; ++i) gsrc[i] += 64;
    __syncthreads();
    bf16x8 af[4], bfr[3];
    #pragma unroll
    for (int i = 0; i < 4; ++i)
      af[i] = *(const bf16x8*)&Al[(wr * 64 + i * 16 + m) * 32 + g * 8];
    #pragma unroll
    for (int j = 0; j < 3; ++j)
      bfr[j] = *(const bf16x8*)&Bl[(wc * 48 + j * 16 + m) * 32 + g * 8];
    #pragma unroll
    for (int i = 0; i < 4; ++i)
      #pragma unroll
      for (int j = 0; j < 3; ++j)
        acc[i][j] = __builtin_amdgcn_mfma_f32_16x16x32_bf16(af[i], bfr[j], acc[i][j], 0, 0, 0);
    __syncthreads();
  }
  #pragma unroll
  for (int i = 0; i < 4; ++i) {
    const int grow = row0 + wr * 64 + i * 16 + g * 4;
    #pragma unroll
    for (int j = 0; j < 3; ++j) {
      const int gcol = wc * 48 + j * 16 + m;
      #pragma unroll
      for (int e = 0; e < 4; ++e)
        m1[(size_t)(grow + e) * 96 + gcol] = __float2bfloat16(tanhf(acc[i][j][e]));
    }
  }
}

// ---------------------------------------------------------------------------
// Kernel 3 (MFMA, one-shot K): m_l = m1 @ w2t[l]^T (K=32 each), fused epilogue
// ---------------------------------------------------------------------------
__global__ __launch_bounds__(256) void k_mix2_16(const __hip_bfloat16* __restrict__ m1,
                                                 const __hip_bfloat16* __restrict__ w2t,
                                                 const float* __restrict__ x,
                                                 const float* __restrict__ xx,
                                                 const float* __restrict__ maa_k,
                                                 const float* __restrict__ maa_v,
                                                 const float* __restrict__ maa_r,
                                                 __hip_bfloat16* __restrict__ xk,
                                                 __hip_bfloat16* __restrict__ xv,
                                                 __hip_bfloat16* __restrict__ xr) {
  __shared__ __align__(16) __hip_bfloat16 Al[128 * 96];     // 24 KB contiguous
  __shared__ __align__(16) __hip_bfloat16 Bl[3 * 64 * 32];  // 12 KB
  const int tid = threadIdx.x;
  const int wid = tid >> 6, lane = tid & 63;
  const int wr = wid >> 1, wc = wid & 1;
  const int row0 = blockIdx.y * 128, col0 = blockIdx.x * 64;
  {
    const char* abase = (const char*)(m1 + (size_t)row0 * 96) + lane * 16;
    #pragma unroll
    for (int i = 0; i < 6; ++i) {
      const int s = wid + i * 4;          // 0..23
      GLD((char*)&Al[0] + s * 1024, abase + s * 1024);
    }
  }
  {
    const char* bbase = (const char*)w2t + (size_t)col0 * 64 + lane * 16;
    #pragma unroll
    for (int i = 0; i < 3; ++i) {
      const int s = wid + i * 4;          // 0..11
      const int l = s >> 2, q = s & 3;
      GLD((char*)&Bl[0] + s * 1024, bbase + (size_t)l * 65536 + q * 1024);
    }
  }
  __syncthreads();
  const int g = lane >> 4, m = lane & 15;
  f32x4 a0[4][2], a1[4][2], a2[4][2];
  #pragma unroll
  for (int i = 0; i < 4; ++i)
    #pragma unroll
    for (int j = 0; j < 2; ++j) {
      a0[i][j] = (f32x4){0.f,0.f,0.f,0.f};
      a1[i][j] = (f32x4){0.f,0.f,0.f,0.f};
      a2[i][j] = (f32x4){0.f,0.f,0.f,0.f};
    }
  #pragma unroll
  for (int l = 0; l < 3; ++l) {
    bf16x8 af[4], bfj[2];
    #pragma unroll
    for (int i = 0; i < 4; ++i)
      af[i] = *(const bf16x8*)&Al[(wr * 64 + i * 16 + m) * 96 + l * 32 + g * 8];
    #pragma unroll
    for (int j = 0; j < 2; ++j)
      bfj[j] = *(const bf16x8*)&Bl[(l * 64 + wc * 32 + j * 16 + m) * 32 + g * 8];
    #pragma unroll
    for (int i = 0; i < 4; ++i)
      #pragma unroll
      for (int j = 0; j < 2; ++j) {
        if (l == 0) a0[i][j] = __builtin_amdgcn_mfma_f32_16x16x32_bf16(af[i], bfj[j], a0[i][j], 0, 0, 0);
        if (l == 1) a1[i][j] = __builtin_amdgcn_mfma_f32_16x16x32_bf16(af[i], bfj[j], a1[i][j], 0, 0, 0);
        if (l == 2) a2[i][j] = __builtin_amdgcn_mfma_f32_16x16x32_bf16(af[i], bfj[j], a2[i][j], 0, 0, 0);
      }
  }
  #pragma unroll
  for (int i = 0; i < 4; ++i) {
    const int grow = row0 + wr * 64 + i * 16 + g * 4;
    #pragma unroll
    for (int j = 0; j < 2; ++j) {
      const int gcol = col0 + wc * 32 + j * 16 + m;
      const float mk_ = maa_k[gcol], mv_ = maa_v[gcol], mr_ = maa_r[gcol];
      #pragma unroll
      for (int e = 0; e < 4; ++e) {
        const size_t off = (size_t)(grow + e) * 1024 + gcol;
        const float xval = x[off], xxv = xx[off];
        xk[off] = __float2bfloat16(fmaf(xxv, mk_ + a0[i][j][e], xval));
        xv[off] = __float2bfloat16(fmaf(xxv, mv_ + a1[i][j][e], xval));
        xr[off] = __float2bfloat16(fmaf(xxv, mr_ + a2[i][j][e], xval));
      }
    }
  }
}

// ---------------------------------------------------------------------------
// Fused convert+transpose of ALL weights: one launch.
// Each block does one 32x32 tile: Wt[n][k] = bf16(W[k][n]).
// ---------------------------------------------------------------------------
__global__ __launch_bounds__(256) void k_cvt_all(const float* __restrict__ w1,
                                                 const float* __restrict__ w2,
                                                 const float* __restrict__ Wr,
                                                 const float* __restrict__ Wk,
                                                 const float* __restrict__ Wvg,
                                                 const float* __restrict__ Wo,
                                                 __hip_bfloat16* __restrict__ w1t,
                                                 __hip_bfloat16* __restrict__ w2t,
                                                 __hip_bfloat16* __restrict__ Wrt,
                                                 __hip_bfloat16* __restrict__ Wkt,
                                                 __hip_bfloat16* __restrict__ Wvgt,
                                                 __hip_bfloat16* __restrict__ Wot) {
  int b = blockIdx.x;
  const float* W; __hip_bfloat16* Wt; int K, N, nx, rel;
  if (b < 96)        { W = w1;  Wt = w1t;  K = 1024; N = 96;   nx = 3;   rel = b; }
  else if (b < 192)  { int l = (b - 96) >> 5; rel = (b - 96) & 31;
                       W = w2 + l * 32768; Wt = w2t + l * 32768; K = 32; N = 1024; nx = 32; }
  else if (b < 1216) { W = Wr;  Wt = Wrt;  K = 1024; N = 1024; nx = 32;  rel = b - 192; }
  else if (b < 2240) { W = Wk;  Wt = Wkt;  K = 1024; N = 1024; nx = 32;  rel = b - 1216; }
  else if (b < 8384) { W = Wvg; Wt = Wvgt; K = 1024; N = 6144; nx = 192; rel = b - 2240; }
  else               { W = Wo;  Wt = Wot;  K = 3072; N = 1024; nx = 32;  rel = b - 8384; }
  int n0 = (rel % nx) * 32, k0 = (rel / nx) * 32;
  __shared__ float tile[32][33];
  int tid = threadIdx.x;
  int c = tid & 31, r = tid >> 5;   // r = 0..7
  #pragma unroll
  for (int i = 0; i < 4; ++i)
    tile[r + i * 8][c] = W[(size_t)(k0 + r + i * 8) * N + n0 + c];
  __syncthreads();
  #pragma unroll
  for (int i = 0; i < 4; ++i)
    Wt[(size_t)(n0 + r + i * 8) * K + k0 + c] = __float2bfloat16(tile[c][r + i * 8]);
}

// ---------------------------------------------------------------------------
// bf16 MFMA GEMM: C(f32) = A(M x K, bf16 row-major) @ Bt(N x K, bf16)^T
// ---------------------------------------------------------------------------
template <int FN, int EPI>
__global__ __launch_bounds__(256) void k_gemm16(const __hip_bfloat16* __restrict__ A,
                                                const __hip_bfloat16* __restrict__ Bt,
                                                float* __restrict__ C,
                                                const int K, const int N) {
  constexpr int BN = FN * 32;
  constexpr int NISS = 8 + BN / 16;
  constexpr int PW = NISS / 4;
  __shared__ __align__(16) __hip_bfloat16 Al[128 * 32];
  __shared__ __align__(16) __hip_bfloat16 Bl[BN * 32];
  const int tid = threadIdx.x;
  const int wid = tid >> 6, lane = tid & 63;
  const int wr = wid >> 1, wc = wid & 1;
  const int row0 = blockIdx.y * 128, col0 = blockIdx.x * BN;
  const char* gsrc[PW];
  char* ldst[PW];
  #pragma unroll
  for (int i = 0; i < PW; ++i) {
    const int s = wid + i * 4;
    if (s < 8) {
      const int r = s * 16 + (lane >> 2);
      gsrc[i] = (const char*)(A + (size_t)(row0 + r) * K) + (lane & 3) * 16;
      ldst[i] = (char*)&Al[0] + s * 1024;
    } else {
      const int r = (s - 8) * 16 + (lane >> 2);
      gsrc[i] = (const char*)(Bt + (size_t)(col0 + r) * K) + (lane & 3) * 16;
      ldst[i] = (char*)&Bl[0] + (s - 8) * 1024;
    }
  }
  f32x4 acc[4][FN];
  #pragma unroll
  for (int i = 0; i < 4; ++i)
    #pragma unroll
    for (int j = 0; j < FN; ++j)
      acc[i][j] = (f32x4){0.f, 0.f, 0.f, 0.f};
  const int g = lane >> 4, m = lane & 15;
  for (int k0 = 0; k0 < K; k0 += 32) {
    #pragma unroll
    for (int i = 0; i < PW; ++i) GLD(ldst[i], gsrc[i]);
    #pragma unroll
    for (int i = 0; i < PW; ++i) gsrc[i] += 64;
    __syncthreads();
    bf16x8 af[4], bfr[FN];
    #pragma unroll
    for (int i = 0; i < 4; ++i)
      af[i] = *(const bf16x8*)&Al[(wr * 64 + i * 16 + m) * 32 + g * 8];
    #pragma unroll
    for (int j = 0; j < FN; ++j)
      bfr[j] = *(const bf16x8*)&Bl[(wc * (BN / 2) + j * 16 + m) * 32 + g * 8];
    #pragma unroll
    for (int i = 0; i < 4; ++i)
      #pragma unroll
      for (int j = 0; j < FN; ++j)
        acc[i][j] = __builtin_amdgcn_mfma_f32_16x16x32_bf16(af[i], bfr[j], acc[i][j], 0, 0, 0);
    __syncthreads();
  }
  #pragma unroll
  for (int i = 0; i < 4; ++i) {
    const int grow = row0 + wr * 64 + i * 16 + g * 4;
    #pragma unroll
    for (int j = 0; j < FN; ++j) {
      const int gcol = col0 + wc * (BN / 2) + j * 16 + m;
      #pragma unroll
      for (int e = 0; e < 4; ++e) {
        float val = acc[i][j][e];
        if (EPI == 1) val = expf(-expf(val));
        C[(size_t)(grow + e) * N + gcol] = val;
      }
    }
  }
}

// ---------------------------------------------------------------------------
// Fused Wvg GEMM: gated[r, c] = (A@B)[r,c] * silu((A@B)[r,c+3072])
// ---------------------------------------------------------------------------
__global__ __launch_bounds__(256) void k_gemm_vg16(const __hip_bfloat16* __restrict__ A,
                                                   const __hip_bfloat16* __restrict__ Bt,
                                                   float* __restrict__ v,
                                                   __hip_bfloat16* __restrict__ ffn) {
  const int K = 1024;
  __shared__ __align__(16) __hip_bfloat16 Al[128 * 32];
  __shared__ __align__(16) __hip_bfloat16 B1l[64 * 32];
  __shared__ __align__(16) __hip_bfloat16 B2l[64 * 32];
  const int tid = threadIdx.x;
  const int wid = tid >> 6, lane = tid & 63;
  const int wr = wid >> 1, wc = wid & 1;
  const int row0 = blockIdx.y * 128, col0 = blockIdx.x * 64;
  const char* gsrc[4];
  char* ldst[4];
  #pragma unroll
  for (int i = 0; i < 4; ++i) {
    const int s = wid + i * 4;
    if (s < 8) {
      const int r = s * 16 + (lane >> 2);
      gsrc[i] = (const char*)(A + (size_t)(row0 + r) * K) + (lane & 3) * 16;
      ldst[i] = (char*)&Al[0] + s * 1024;
    } else if (s < 12) {
      const int r = col0 + (s - 8) * 16 + (lane >> 2);
      gsrc[i] = (const char*)(Bt + (size_t)r * K) + (lane & 3) * 16;
      ldst[i] = (char*)&B1l[0] + (s - 8) * 1024;
    } else {
      const int r = 3072 + col0 + (s - 12) * 16 + (lane >> 2);
      gsrc[i] = (const char*)(Bt + (size_t)r * K) + (lane & 3) * 16;
      ldst[i] = (char*)&B2l[0] + (s - 12) * 1024;
    }
  }
  f32x4 a1[4][2], a2[4][2];
  #pragma unroll
  for (int i = 0; i < 4; ++i)
    #pragma unroll
    for (int j = 0; j < 2; ++j) {
      a1[i][j] = (f32x4){0.f, 0.f, 0.f, 0.f};
      a2[i][j] = (f32x4){0.f, 0.f, 0.f, 0.f};
    }
  const int g = lane >> 4, m = lane & 15;
  for (int k0 = 0; k0 < K; k0 += 32) {
    #pragma unroll
    for (int i = 0; i < 4; ++i) GLD(ldst[i], gsrc[i]);
    #pragma unroll
    for (int i = 0; i < 4; ++i) gsrc[i] += 64;
    __syncthreads();
    bf16x8 af[4], b1f[2], b2f[2];
    #pragma unroll
    for (int i = 0; i < 4; ++i)
      af[i] = *(const bf16x8*)&Al[(wr * 64 + i * 16 + m) * 32 + g * 8];
    #pragma unroll
    for (int j = 0; j < 2; ++j) {
      b1f[j] = *(const bf16x8*)&B1l[(wc * 32 + j * 16 + m) * 32 + g * 8];
      b2f[j] = *(const bf16x8*)&B2l[(wc * 32 + j * 16 + m) * 32 + g * 8];
    }
    #pragma unroll
    for (int i = 0; i < 4; ++i)
      #pragma unroll
      for (int j = 0; j < 2; ++j) {
        a1[i][j] = __builtin_amdgcn_mfma_f32_16x16x32_bf16(af[i], b1f[j], a1[i][j], 0, 0, 0);
        a2[i][j] = __builtin_amdgcn_mfma_f32_16x16x32_bf16(af[i], b2f[j], a2[i][j], 0, 0, 0);
      }
    __syncthreads();
  }
  const bool to_v = (col0 < 1024);
  #pragma unroll
  for (int i = 0; i < 4; ++i) {
    const int grow = row0 + wr * 64 + i * 16 + g * 4;
    #pragma unroll
    for (int j = 0; j < 2; ++j) {
      const int gcol = col0 + wc * 32 + j * 16 + m;
      #pragma unroll
      for (int e = 0; e < 4; ++e) {
        float gate = a2[i][j][e];
        float val = a1[i][j][e] * (gate / (1.f + expf(-gate)));
        if (to_v) v[(size_t)(grow + e) * 1024 + gcol] = val;
        else ffn[(size_t)(grow + e) * 2048 + (gcol - 1024)] = __float2bfloat16(val);
      }
    }
  }
}

// ---------------------------------------------------------------------------
// Final GEMM: out = [ln16 (4096x1024) | ffn16 (4096x2048)] @ Wo_t^T
// ---------------------------------------------------------------------------
__global__ __launch_bounds__(256) void k_gemm_wo16(const __hip_bfloat16* __restrict__ A1,
                                                   const __hip_bfloat16* __restrict__ A2,
                                                   const __hip_bfloat16* __restrict__ Bt,
                                                   float* __restrict__ C) {
  const int Kt = 3072;
  __shared__ __align__(16) __hip_bfloat16 Al[128 * 32];
  __shared__ __align__(16) __hip_bfloat16 Bl[64 * 32];
  const int tid = threadIdx.x;
  const int wid = tid >> 6, lane = tid & 63;
  const int wr = wid >> 1, wc = wid & 1;
  const int row0 = blockIdx.y * 128, col0 = blockIdx.x * 64;
  const char* gsrc[3];
  char* ldst[3];
  #pragma unroll
  for (int i = 0; i < 3; ++i) {
    const int s = wid + i * 4;
    if (s < 8) {
      const int r = s * 16 + (lane >> 2);
      gsrc[i] = (const char*)(A1 + (size_t)(row0 + r) * 1024) + (lane & 3) * 16;
      ldst[i] = (char*)&Al[0] + s * 1024;
    } else {
      const int r = col0 + (s - 8) * 16 + (lane >> 2);
      gsrc[i] = (const char*)(Bt + (size_t)r * Kt) + (lane & 3) * 16;
      ldst[i] = (char*)&Bl[0] + (s - 8) * 1024;
    }
  }
  f32x4 acc[4][2];
  #pragma unroll
  for (int i = 0; i < 4; ++i)
    #pragma unroll
    for (int j = 0; j < 2; ++j)
      acc[i][j] = (f32x4){0.f, 0.f, 0.f, 0.f};
  const int g = lane >> 4, m = lane & 15;

  #define WO_STEP() do {                                                          \
    _Pragma("unroll")                                                             \
    for (int i = 0; i < 3; ++i) GLD(ldst[i], gsrc[i]);                            \
    _Pragma("unroll")                                                             \
    for (int i = 0; i < 3; ++i) gsrc[i] += 64;                                    \
    __syncthreads();                                                              \
    bf16x8 af[4], bfr[2];                                                         \
    _Pragma("unroll")                                                             \
    for (int i = 0; i < 4; ++i)                                                   \
      af[i] = *(const bf16x8*)&Al[(wr * 64 + i * 16 + m) * 32 + g * 8];           \
    _Pragma("unroll")                                                             \
    for (int j = 0; j < 2; ++j)                                                   \
      bfr[j] = *(const bf16x8*)&Bl[(wc * 32 + j * 16 + m) * 32 + g * 8];          \
    _Pragma("unroll")                                                             \
    for (int i = 0; i < 4; ++i)                                                   \
      _Pragma("unroll")                                                           \
      for (int j = 0; j < 2; ++j)                                                 \
        acc[i][j] = __builtin_amdgcn_mfma_f32_16x16x32_bf16(af[i], bfr[j],        \
                                                            acc[i][j], 0, 0, 0); \
    __syncthreads();                                                              \
  } while (0)

  for (int k0 = 0; k0 < 1024; k0 += 32) WO_STEP();
  #pragma unroll
  for (int i = 0; i < 3; ++i) {
    const int s = wid + i * 4;
    if (s < 8) {
      const int r = s * 16 + (lane >> 2);
      gsrc[i] = (const char*)(A2 + (size_t)(row0 + r) * 2048) + (lane & 3) * 16;
    }
  }
  for (int k0 = 0; k0 < 2048; k0 += 32) WO_STEP();
  #undef WO_STEP

  #pragma unroll
  for (int i = 0; i < 4; ++i) {
    const int grow = row0 + wr * 64 + i * 16 + g * 4;
    #pragma unroll
    for (int j = 0; j < 2; ++j) {
      const int gcol = col0 + wc * 32 + j * 16 + m;
      #pragma unroll
      for (int e = 0; e < 4; ++e)
        C[(size_t)(grow + e) * 1024 + gcol] = acc[i][j][e];
    }
  }
}

// ---------------------------------------------------------------------------
// WKV6 phase 1 (restructured): per-chunk local recurrence from S=0.
// 4 waves, wave w owns k-rows [16w,16w+16), lane = v column.
// u-term via per-lane product + 16-lane butterfly (no readlane, no per-step
// barrier). Cross-wave y reduction batched over TT=8 steps (2 barriers/8
// steps instead of 2/step). r/e/v prefetched per batch.
// ---------------------------------------------------------------------------
#define TTn 8
__global__ __launch_bounds__(256) void k_wkv1(const float* __restrict__ r,
                                              const float* __restrict__ e,
                                              const float* __restrict__ v,
                                              const float* __restrict__ u,
                                              float* __restrict__ o,
                                              float* __restrict__ Dcum,
                                              float* __restrict__ Dtot,
                                              float* __restrict__ Inc) {
  int blk = blockIdx.x;
  int c = blk & (NCn - 1);
  int bh = blk >> 4;
  int b = bh >> 4, h = bh & 15;
  int tid = threadIdx.x, wave = tid >> 6, lane = tid & 63;
  size_t base = (size_t)b * Tn * Cn + (size_t)h * 64 + (size_t)c * Ln * Cn;
  int jbase = wave * 16 + (lane & 15);
  float uv = u[h * 64 + jbase];
  float st[16];
  #pragma unroll
  for (int i = 0; i < 16; ++i) st[i] = 0.f;
  float cum = 1.f;
  __shared__ float yp[4][TTn][64];
  for (int tb = 0; tb < Ln / TTn; ++tb) {
    // prefetch batch inputs
    float rv8[TTn], ev8[TTn], vv8[TTn];
    #pragma unroll
    for (int tt = 0; tt < TTn; ++tt) {
      size_t off = base + (size_t)(tb * TTn + tt) * Cn;
      rv8[tt] = r[off + jbase];
      ev8[tt] = e[off + jbase];
      vv8[tt] = v[off + lane];
    }
    float yb[TTn];
    #pragma unroll
    for (int tt = 0; tt < TTn; ++tt) {
      const float rv = rv8[tt], ev = ev8[tt], vv = vv8[tt];
      if (lane < 16)
        Dcum[base + (size_t)(tb * TTn + tt) * Cn + jbase] = cum;
      cum *= ev;
      // u-term: y_u = vv * sum_j r_j*u_j*(1-e_j)  (butterfly over 16-lane group)
      float p = rv * uv * (1.f - ev);
      p += __shfl_xor(p, 1, 16);
      p += __shfl_xor(p, 2, 16);
      p += __shfl_xor(p, 4, 16);
      p += __shfl_xor(p, 8, 16);
      float y = p * vv;
      #pragma unroll
      for (int jj = 0; jj < 16; ++jj) {
        float rj = rdlane(rv, jj);
        float ej = rdlane(ev, jj);
        float kv = fmaf(-ej, vv, vv);       // (1-ej)*vv
        y = fmaf(rj, st[jj], y);
        st[jj] = fmaf(st[jj], ej, kv);
      }
      yb[tt] = y;
    }
    #pragma unroll
    for (int tt = 0; tt < TTn; ++tt) yp[wave][tt][lane] = yb[tt];
    __syncthreads();
    #pragma unroll
    for (int q = 0; q < TTn / 4; ++q) {
      int tt = wave * (TTn / 4) + q;
      size_t off = base + (size_t)(tb * TTn + tt) * Cn;
      o[off + lane] = yp[0][tt][lane] + yp[1][tt][lane] + yp[2][tt][lane] + yp[3][tt][lane];
    }
    __syncthreads();
  }
  size_t sbase = ((size_t)bh * NCn + c) * 4096;
  #pragma unroll
  for (int jj = 0; jj < 16; ++jj)
    Inc[sbase + (size_t)(wave * 16 + jj) * 64 + lane] = st[jj];
  if (lane < 16)
    Dtot[((size_t)bh * NCn + c) * 64 + jbase] = cum;
}

// ---------------------------------------------------------------------------
// WKV6 phase 2: sequential combine of chunk states, in place.
// ---------------------------------------------------------------------------
__global__ __launch_bounds__(256) void k_wkv2(float* __restrict__ S,
                                              const float* __restrict__ Dtot) {
  int bh = blockIdx.x;
  int tid = threadIdx.x;
  float4 s[4];
  #pragma unroll
  for (int j = 0; j < 4; ++j) { s[j].x = 0.f; s[j].y = 0.f; s[j].z = 0.f; s[j].w = 0.f; }
  size_t sb = (size_t)bh * NCn * 4096;
  for (int c = 0; c < NCn; ++c) {
    float4* entry = (float4*)(S + sb + (size_t)c * 4096);
    const float* dt = Dtot + ((size_t)bh * NCn + c) * 64;
    #pragma unroll
    for (int j = 0; j < 4; ++j) {
      int idx4 = tid + j * 256;
      int k = idx4 >> 4;
      float d = dt[k];
      float4 inc = entry[idx4];
      float4 cur = s[j];
      entry[idx4] = cur;
      s[j].x = fmaf(cur.x, d, inc.x);
      s[j].y = fmaf(cur.y, d, inc.y);
      s[j].z = fmaf(cur.z, d, inc.z);
      s[j].w = fmaf(cur.w, d, inc.w);
    }
  }
}

// ---------------------------------------------------------------------------
// WKV6 phase 3: o_t += (r_t * Dcum_t) . S_start_{chunk(t)}
// ---------------------------------------------------------------------------
__global__ __launch_bounds__(256) void k_wkv3(const float* __restrict__ r,
                                              const float* __restrict__ Dcum,
                                              const float* __restrict__ S,
                                              float* __restrict__ o) {
  int blk = blockIdx.x;
  int c = blk & (NCn - 1);
  if (c == 0) return;
  int bh = blk >> 4;
  int b = bh >> 4, h = bh & 15;
  int tid = threadIdx.x, wave = tid >> 6, lane = tid & 63;
  const float* Sg = S + ((size_t)bh * NCn + c) * 4096;
  float sreg[64];
  #pragma unroll
  for (int k = 0; k < 64; ++k) sreg[k] = Sg[k * 64 + lane];
  size_t base = (size_t)b * Tn * Cn + (size_t)h * 64 + (size_t)c * Ln * Cn;
  for (int ti = 0; ti < 16; ++ti) {
    int t = wave * 16 + ti;
    size_t off = base + (size_t)t * Cn;
    float rd = r[off + lane] * Dcum[off + lane];
    float y = 0.f;
    #pragma unroll
    for (int k = 0; k < 64; ++k)
      y = fmaf(rdlane(rd, k), sreg[k], y);
    o[off + lane] += y;
  }
}

// ---------------------------------------------------------------------------
// LayerNorm over C=1024 -> ln16 (bf16 4096x1024)
// ---------------------------------------------------------------------------
__global__ __launch_bounds__(256) void k_ln(const float* __restrict__ o,
                                            const float* __restrict__ g,
                                            const float* __restrict__ bta,
                                            __hip_bfloat16* __restrict__ ln16) {
  int bt = blockIdx.x, tid = threadIdx.x;
  const float4* row = (const float4*)(o + (size_t)bt * 1024);
  float4 v = row[tid];
  float s = v.x + v.y + v.z + v.w;
  float s2 = fmaf(v.x, v.x, fmaf(v.y, v.y, fmaf(v.z, v.z, v.w * v.w)));
  #pragma unroll
  for (int m = 1; m < 64; m <<= 1) {
    s += __shfl_xor(s, m, 64);
    s2 += __shfl_xor(s2, m, 64);
  }
  __shared__ float rs[4], rq[4];
  if ((tid & 63) == 0) { rs[tid >> 6] = s; rq[tid >> 6] = s2; }
  __syncthreads();
  s = rs[0] + rs[1] + rs[2] + rs[3];
  s2 = rq[0] + rq[1] + rq[2] + rq[3];
  float mu = s * (1.f / 1024.f);
  float var = s2 * (1.f / 1024.f) - mu * mu;
  float rstd = rsqrtf(var + 1e-5f);
  float4 gv = ((const float4*)g)[tid];
  float4 bv = ((const float4*)bta)[tid];
  ushort4 outv;
  outv.x = bfbits(fmaf((v.x - mu) * rstd, gv.x, bv.x));
  outv.y = bfbits(fmaf((v.y - mu) * rstd, gv.y, bv.y));
  outv.z = bfbits(fmaf((v.z - mu) * rstd, gv.z, bv.z));
  outv.w = bfbits(fmaf((v.w - mu) * rstd, gv.w, bv.w));
  ((ushort4*)((unsigned short*)ln16 + (size_t)bt * 1024))[tid] = outv;
}

// ---------------------------------------------------------------------------
extern "C" void kernel_launch(void* const* d_in, const int* in_sizes, int n_in,
                              void* d_out, int out_size, void* d_ws, size_t ws_size,
                              hipStream_t stream) {
  const float* x     = (const float*)d_in[0];
  const float* maa_x = (const float*)d_in[1];
  const float* maa_k = (const float*)d_in[2];
  const float* maa_v = (const float*)d_in[3];
  const float* maa_r = (const float*)d_in[4];
  const float* w1    = (const float*)d_in[5];
  const float* w2    = (const float*)d_in[6];
  const float* u     = (const float*)d_in[7];
  const float* Wr    = (const float*)d_in[8];
  const float* Wk    = (const float*)d_in[9];
  const float* Wvg   = (const float*)d_in[10];
  const float* Wo    = (const float*)d_in[11];
  const float* ln_g  = (const float*)d_in[12];
  const float* ln_b  = (const float*)d_in[13];
  float* out = (float*)d_out;
  float* ws = (float*)d_ws;

  // Workspace layout (floats), total 36M floats = 144 MB.
  const size_t M1 = 1048576;
  float* xx    = ws;                        //  0   .. 4M   f32  -> oo
  __hip_bfloat16* xxx16 = (__hip_bfloat16*)(ws + 4 * M1);  // 4M..6M (bf16) -> rr slot
  __hip_bfloat16* m1_16 = (__hip_bfloat16*)(ws + 8 * M1);  // 4096x96 bf16 -> Dtot
  __hip_bfloat16* w1t = (__hip_bfloat16*)(ws + 8 * M1 + 393216); // 96x1024 bf16
  __hip_bfloat16* w2t = (__hip_bfloat16*)(ws + 8 * M1 + 442368); // 3x1024x32 bf16
  __hip_bfloat16* xk16 = (__hip_bfloat16*)(ws + 8 * M1 + 524288);   // 8.5M..10.5M
  __hip_bfloat16* xv16 = (__hip_bfloat16*)(ws + 10 * M1 + 524288);  // 10.5M..12.5M
  __hip_bfloat16* xr16 = (__hip_bfloat16*)(ws + 12 * M1 + 524288);  // 12.5M..14.5M
  float* ee    = ws + 14 * M1 + 524288;     // 14.5M..18.5M f32
  float* vv    = ws + 18 * M1 + 524288;     // 18.5M..22.5M f32
  float* Sbuf  = ws + 22 * M1 + 524288;     // 22.5M..26.5M f32 Inc/S_start -> ln16
  __hip_bfloat16* ffn16 = (__hip_bfloat16*)(ws + 26 * M1 + 524288); // 26.5M..30.5M
  __hip_bfloat16* Wr16t = (__hip_bfloat16*)(ws + 30 * M1 + 524288); // 0.5M floats
  __hip_bfloat16* Wk16t = (__hip_bfloat16*)(ws + 31 * M1);          // 0.5M floats
  __hip_bfloat16* Wvg16t = (__hip_bfloat16*)(ws + 31 * M1 + 524288);// 3M floats
  __hip_bfloat16* Wo16t = (__hip_bfloat16*)(ws + 34 * M1 + 524288); // 1.5M floats
  float* rr = ws + 4 * M1;                  // overlays xxx16 (dead after mix1)
  float* oo = xx;
  float* Dcum = ws + 8 * M1 + 524288;       // overlaps xk16/xv16 (dead by wkv1)
  float* Dtot = (float*)m1_16;              // m1 dead after mix2
  __hip_bfloat16* ln16 = (__hip_bfloat16*)Sbuf;  // after wkv3

  // all weight converts (B^T bf16) in one launch
  k_cvt_all<<<11456, 256, 0, stream>>>(w1, w2, Wr, Wk, Wvg, Wo,
                                       w1t, w2t, Wr16t, Wk16t, Wvg16t, Wo16t);

  k_prep<<<4096, 256, 0, stream>>>(x, maa_x, xx, xxx16);
  // m1 = tanh(xxx @ w1) via MFMA (bf16 out)
  k_mix1_16<<<32, 256, 0, stream>>>(xxx16, w1t, m1_16);
  // fused m2 GEMM + token-mix epilogue -> xk/xv/xr bf16
  k_mix2_16<<<dim3(16, 32), 256, 0, stream>>>(m1_16, w2t, x, xx, maa_k, maa_v, maa_r,
                                              xk16, xv16, xr16);
  // r = xr @ Wr (f32 out into xxx slot; xxx16 dead after mix1)
  k_gemm16<2, 0><<<dim3(16, 32), 256, 0, stream>>>(xr16, Wr16t, rr, 1024, 1024);
  // gated vg = xv @ Wvg -> v (f32) + ffn (bf16)
  k_gemm_vg16<<<dim3(48, 32), 256, 0, stream>>>(xv16, Wvg16t, vv, ffn16);
  // e = exp(-exp(xk @ Wk)) (f32)
  k_gemm16<2, 1><<<dim3(16, 32), 256, 0, stream>>>(xk16, Wk16t, ee, 1024, 1024);
  // WKV6 chunk-parallel scan
  k_wkv1<<<64 * NCn, 256, 0, stream>>>(rr, ee, vv, u, oo, Dcum, Dtot, Sbuf);
  k_wkv2<<<64, 256, 0, stream>>>(Sbuf, Dtot);
  k_wkv3<<<64 * NCn, 256, 0, stream>>>(rr, Dcum, Sbuf, oo);
  // LayerNorm -> bf16 (Sbuf slot, S dead after wkv3)
  k_ln<<<4096, 256, 0, stream>>>(oo, ln_g, ln_b, ln16);
  // out = [ln16 | ffn16] @ Wo
  k_gemm_wo16<<<dim3(16, 32), 256, 0, stream>>>(ln16, ffn16, Wo16t, out);
}